// Round 1
// baseline (316.554 us; speedup 1.0000x reference)
//
#include <hip/hip_runtime.h>
#include <hip/hip_bf16.h>

typedef float f32x4 __attribute__((ext_vector_type(4)));
typedef short bf16x8 __attribute__((ext_vector_type(8)));

#define MFMA16(A,B,C) __builtin_amdgcn_mfma_f32_16x16x32_bf16(A,B,C,0,0,0)

__device__ __forceinline__ unsigned short f2bf(float f) {
    union { float f; unsigned u; } x; x.f = f;
    return (unsigned short)((x.u + 0x7FFFu + ((x.u >> 16) & 1u)) >> 16);
}

// ---------------- Kernel 1: WT[n][k] = W_cat[k][n] as bf16 (n in 0..383) ---------
__global__ void prep_wt(const float* __restrict__ Wq, const float* __restrict__ Wk,
                        const float* __restrict__ Wv, unsigned short* __restrict__ WT) {
    int n = blockIdx.x;
    const float* src; int c;
    if (n < 128)      { src = Wq; c = n; }
    else if (n < 256) { src = Wk; c = n - 128; }
    else              { src = Wv; c = n - 256; }
    for (int k = threadIdx.x; k < 1024; k += 256)
        WT[n * 1024 + k] = f2bf(src[k * 128 + c]);
}

// ---------------- Kernel 2: QKV projection. ------------------------------------
// Q[m][0:128] (x0.125 folded), K[m][0:128] row-major bf16; V written transposed
// VT[b][v][s] bf16. Block: 64 rows x 192 cols (blockIdx.y selects col half).
__global__ __launch_bounds__(256) void proj(const float* __restrict__ X,
        const unsigned short* __restrict__ WT, unsigned short* __restrict__ Qb,
        unsigned short* __restrict__ Kb, unsigned short* __restrict__ VTb) {
    int wave = threadIdx.x >> 6, lane = threadIdx.x & 63;
    int lr = lane & 15, lg = lane >> 4;
    int m0 = blockIdx.x * 64 + wave * 16;     // global row (b*4096+s)
    int nbase = blockIdx.y * 12;              // n-tile base

    f32x4 acc[12];
#pragma unroll
    for (int i = 0; i < 12; ++i) acc[i] = f32x4{0.f,0.f,0.f,0.f};

    const float* xrow = X + (size_t)(m0 + lr) * 1024;
    for (int kk = 0; kk < 1024; kk += 32) {
        float4 x0 = *(const float4*)(xrow + kk + lg * 8);
        float4 x1 = *(const float4*)(xrow + kk + lg * 8 + 4);
        bf16x8 a;
        a[0] = (short)f2bf(x0.x); a[1] = (short)f2bf(x0.y);
        a[2] = (short)f2bf(x0.z); a[3] = (short)f2bf(x0.w);
        a[4] = (short)f2bf(x1.x); a[5] = (short)f2bf(x1.y);
        a[6] = (short)f2bf(x1.z); a[7] = (short)f2bf(x1.w);
#pragma unroll
        for (int nt = 0; nt < 12; ++nt) {
            bf16x8 bfr = *(const bf16x8*)(WT + (size_t)((nbase + nt) * 16 + lr) * 1024 + kk + lg * 8);
            acc[nt] = MFMA16(a, bfr, acc[nt]);
        }
    }
    int b = m0 >> 12;
    int sloc = m0 & 4095;
#pragma unroll
    for (int nt = 0; nt < 12; ++nt) {
        int ntg = nbase + nt;
        if (ntg < 16) {
            float sc = (ntg < 8) ? 0.125f : 1.0f;   // fold QK^T scale into Q
            unsigned short* dst = (ntg < 8) ? Qb : Kb;
            int col = (ntg & 7) * 16 + lr;
#pragma unroll
            for (int r = 0; r < 4; ++r) {
                int m = m0 + 4 * lg + r;
                dst[(size_t)m * 128 + col] = f2bf(acc[nt][r] * sc);
            }
        } else {
            int vcol = (ntg - 16) * 16 + lr;
            ushort4 pk;
            pk.x = f2bf(acc[nt][0]); pk.y = f2bf(acc[nt][1]);
            pk.z = f2bf(acc[nt][2]); pk.w = f2bf(acc[nt][3]);
            *(ushort4*)(VTb + (size_t)(b * 128 + vcol) * 4096 + sloc + 4 * lg) = pk;
        }
    }
}

// ---------------- Kernel 3: flash attention, one softmax component per block.z --
// Wave: 16 q-rows, loop 32-key tiles. P transposed via per-wave LDS scratch.
__global__ __launch_bounds__(256) void attn(const unsigned short* __restrict__ Qb,
        const unsigned short* __restrict__ Kb, const unsigned short* __restrict__ VTb,
        float* __restrict__ O1, float* __restrict__ O2) {
    int wave = threadIdx.x >> 6, lane = threadIdx.x & 63;
    int lr = lane & 15, lg = lane >> 4;
    int b = blockIdx.y, comp = blockIdx.z;
    int q0 = blockIdx.x * 64 + wave * 16;
    int dof = comp * 64;
    float* Ob = comp ? O2 : O1;

    __shared__ __align__(16) unsigned short plds[4][16][40];  // pad 32->40

    const unsigned short* qrow = Qb + (size_t)(b * 4096 + q0 + lr) * 128 + dof + lg * 8;
    bf16x8 qf0 = *(const bf16x8*)(qrow);
    bf16x8 qf1 = *(const bf16x8*)(qrow + 32);

    f32x4 o[8];
#pragma unroll
    for (int i = 0; i < 8; ++i) o[i] = f32x4{0.f,0.f,0.f,0.f};
    float mrow[4] = {-1e30f,-1e30f,-1e30f,-1e30f};
    float lrow[4] = {0.f,0.f,0.f,0.f};

    const unsigned short* kbase = Kb + (size_t)b * 4096 * 128 + dof + lg * 8;
    const unsigned short* vbase = VTb + (size_t)(b * 128 + lr) * 4096 + lg * 8;

    for (int k0 = 0; k0 < 4096; k0 += 32) {
        f32x4 s[2];
#pragma unroll
        for (int t = 0; t < 2; ++t) {
            f32x4 sa = f32x4{0.f,0.f,0.f,0.f};
            const unsigned short* kp = kbase + (size_t)(k0 + t * 16 + lr) * 128;
            sa = MFMA16(qf0, *(const bf16x8*)kp, sa);
            sa = MFMA16(qf1, *(const bf16x8*)(kp + 32), sa);
            s[t] = sa;
        }
        float pm[4];
#pragma unroll
        for (int r = 0; r < 4; ++r) pm[r] = fmaxf(s[0][r], s[1][r]);
#pragma unroll
        for (int off = 1; off < 16; off <<= 1) {
#pragma unroll
            for (int r = 0; r < 4; ++r)
                pm[r] = fmaxf(pm[r], __shfl_xor(pm[r], off, 64));
        }
        float alpha[4], psum[4];
#pragma unroll
        for (int r = 0; r < 4; ++r) {
            float mn = fmaxf(mrow[r], pm[r]);
            alpha[r] = __expf(mrow[r] - mn);
            mrow[r] = mn;
            psum[r] = 0.f;
        }
#pragma unroll
        for (int t = 0; t < 2; ++t)
#pragma unroll
            for (int r = 0; r < 4; ++r) {
                float p = __expf(s[t][r] - mrow[r]);
                psum[r] += p;
                plds[wave][4 * lg + r][t * 16 + lr] = f2bf(p);
            }
#pragma unroll
        for (int off = 1; off < 16; off <<= 1) {
#pragma unroll
            for (int r = 0; r < 4; ++r)
                psum[r] += __shfl_xor(psum[r], off, 64);
        }
#pragma unroll
        for (int r = 0; r < 4; ++r) lrow[r] = lrow[r] * alpha[r] + psum[r];
#pragma unroll
        for (int vt = 0; vt < 8; ++vt)
#pragma unroll
            for (int r = 0; r < 4; ++r) o[vt][r] *= alpha[r];

        asm volatile("" ::: "memory");                      // order LDS write -> read
        bf16x8 pf = *(const bf16x8*)(&plds[wave][lr][lg * 8]);
        asm volatile("" ::: "memory");                      // keep read before next-iter writes

#pragma unroll
        for (int vt = 0; vt < 8; ++vt) {
            bf16x8 vf = *(const bf16x8*)(vbase + (size_t)vt * 16 * 4096 + k0);
            o[vt] = MFMA16(pf, vf, o[vt]);
        }
    }
    float rl[4];
#pragma unroll
    for (int r = 0; r < 4; ++r) rl[r] = 1.0f / lrow[r];
#pragma unroll
    for (int vt = 0; vt < 8; ++vt)
#pragma unroll
        for (int r = 0; r < 4; ++r) {
            size_t idx = (size_t)(b * 4096 + q0 + 4 * lg + r) * 128 + vt * 16 + lr;
            Ob[idx] = o[vt][r] * rl[r];
        }
}

// ---------------- Kernel 4: out = O1 - lam * O2 ---------------------------------
__global__ __launch_bounds__(256) void combine(const float* __restrict__ O1,
        const float* __restrict__ O2, const float* __restrict__ lamp,
        float* __restrict__ out) {
    float lam = lamp[0];
    int i = blockIdx.x * blockDim.x + threadIdx.x;
    float4 a = ((const float4*)O1)[i];
    float4 c = ((const float4*)O2)[i];
    float4 r;
    r.x = a.x - lam * c.x; r.y = a.y - lam * c.y;
    r.z = a.z - lam * c.z; r.w = a.w - lam * c.w;
    ((float4*)out)[i] = r;
}

extern "C" void kernel_launch(void* const* d_in, const int* in_sizes, int n_in,
                              void* d_out, int out_size, void* d_ws, size_t ws_size,
                              hipStream_t stream) {
    const float* X   = (const float*)d_in[0];
    const float* Wq  = (const float*)d_in[1];
    const float* Wk  = (const float*)d_in[2];
    const float* Wv  = (const float*)d_in[3];
    const float* lam = (const float*)d_in[4];
    float* out = (float*)d_out;

    char* ws = (char*)d_ws;
    unsigned short* WT  = (unsigned short*)(ws);                       // 384x1024 bf16
    unsigned short* Qb  = (unsigned short*)(ws + 786432);              // 8192x128 bf16
    unsigned short* Kb  = (unsigned short*)(ws + 786432 + 2097152);    // 8192x128 bf16
    unsigned short* VTb = (unsigned short*)(ws + 786432 + 2*2097152);  // 2x128x4096 bf16
    float* O1 = (float*)(ws + 786432 + 3*2097152);                     // 2x4096x128 f32
    float* O2 = (float*)(ws + 786432 + 3*2097152 + 4194304);

    prep_wt<<<dim3(384), dim3(256), 0, stream>>>(Wq, Wk, Wv, WT);
    proj<<<dim3(128, 2), dim3(256), 0, stream>>>(X, WT, Qb, Kb, VTb);
    attn<<<dim3(64, 2, 2), dim3(256), 0, stream>>>(Qb, Kb, VTb, O1, O2);
    combine<<<dim3(1024), dim3(256), 0, stream>>>(O1, O2, lam, out);
}

// Round 2
// 239.495 us; speedup vs baseline: 1.3218x; 1.3218x over previous
//
#include <hip/hip_runtime.h>
#include <hip/hip_bf16.h>

typedef float f32x4 __attribute__((ext_vector_type(4)));
typedef short bf16x8 __attribute__((ext_vector_type(8)));

#define MFMA16(A,B,C) __builtin_amdgcn_mfma_f32_16x16x32_bf16(A,B,C,0,0,0)

__device__ __forceinline__ unsigned short f2bf(float f) {
    union { float f; unsigned u; } x; x.f = f;
    return (unsigned short)((x.u + 0x7FFFu + ((x.u >> 16) & 1u)) >> 16);
}

// ---------------- Kernel 1: WT[n][k] = W_cat[k][n] as bf16 (n in 0..383) ---------
__global__ void prep_wt(const float* __restrict__ Wq, const float* __restrict__ Wk,
                        const float* __restrict__ Wv, unsigned short* __restrict__ WT) {
    int n = blockIdx.x;
    const float* src; int c;
    if (n < 128)      { src = Wq; c = n; }
    else if (n < 256) { src = Wk; c = n - 128; }
    else              { src = Wv; c = n - 256; }
    for (int k = threadIdx.x; k < 1024; k += 256)
        WT[n * 1024 + k] = f2bf(src[k * 128 + c]);
}

// ---------------- Kernel 2: QKV projection. ------------------------------------
// Q[m][0:128] (x 0.125*log2e folded -> exp2 domain), K[m][0:128] row-major bf16;
// V transposed VT[b][v][s] bf16.
__global__ __launch_bounds__(256) void proj(const float* __restrict__ X,
        const unsigned short* __restrict__ WT, unsigned short* __restrict__ Qb,
        unsigned short* __restrict__ Kb, unsigned short* __restrict__ VTb) {
    int wave = threadIdx.x >> 6, lane = threadIdx.x & 63;
    int lr = lane & 15, lg = lane >> 4;
    int m0 = blockIdx.x * 64 + wave * 16;     // global row (b*4096+s)
    int nbase = blockIdx.y * 12;              // n-tile base

    f32x4 acc[12];
#pragma unroll
    for (int i = 0; i < 12; ++i) acc[i] = f32x4{0.f,0.f,0.f,0.f};

    const float* xrow = X + (size_t)(m0 + lr) * 1024;
    for (int kk = 0; kk < 1024; kk += 32) {
        float4 x0 = *(const float4*)(xrow + kk + lg * 8);
        float4 x1 = *(const float4*)(xrow + kk + lg * 8 + 4);
        bf16x8 a;
        a[0] = (short)f2bf(x0.x); a[1] = (short)f2bf(x0.y);
        a[2] = (short)f2bf(x0.z); a[3] = (short)f2bf(x0.w);
        a[4] = (short)f2bf(x1.x); a[5] = (short)f2bf(x1.y);
        a[6] = (short)f2bf(x1.z); a[7] = (short)f2bf(x1.w);
#pragma unroll
        for (int nt = 0; nt < 12; ++nt) {
            bf16x8 bfr = *(const bf16x8*)(WT + (size_t)((nbase + nt) * 16 + lr) * 1024 + kk + lg * 8);
            acc[nt] = MFMA16(a, bfr, acc[nt]);
        }
    }
    int b = m0 >> 12;
    int sloc = m0 & 4095;
#pragma unroll
    for (int nt = 0; nt < 12; ++nt) {
        int ntg = nbase + nt;
        if (ntg < 16) {
            // fold (1/8)*log2(e) into Q so attn uses exp2 directly
            float sc = (ntg < 8) ? 0.1803368801f : 1.0f;
            unsigned short* dst = (ntg < 8) ? Qb : Kb;
            int col = (ntg & 7) * 16 + lr;
#pragma unroll
            for (int r = 0; r < 4; ++r) {
                int m = m0 + 4 * lg + r;
                dst[(size_t)m * 128 + col] = f2bf(acc[nt][r] * sc);
            }
        } else {
            int vcol = (ntg - 16) * 16 + lr;
            ushort4 pk;
            pk.x = f2bf(acc[nt][0]); pk.y = f2bf(acc[nt][1]);
            pk.z = f2bf(acc[nt][2]); pk.w = f2bf(acc[nt][3]);
            *(ushort4*)(VTb + (size_t)(b * 128 + vcol) * 4096 + sloc + 4 * lg) = pk;
        }
    }
}

// ---------------- Kernel 3: flash attention, no-max softmax, k-split partials ---
// blockIdx.z = comp*2 + split. Each wave: 16 q rows, keys [split*2048, +2048).
// Writes unnormalized O partials (f32) and row-sum partials l.
__global__ __launch_bounds__(256) void attn(const unsigned short* __restrict__ Qb,
        const unsigned short* __restrict__ Kb, const unsigned short* __restrict__ VTb,
        float* __restrict__ Opart, float* __restrict__ Lpart) {
    int wave = threadIdx.x >> 6, lane = threadIdx.x & 63;
    int lr = lane & 15, lg = lane >> 4;
    int b = blockIdx.y;
    int comp = blockIdx.z >> 1, split = blockIdx.z & 1;
    int q0 = blockIdx.x * 64 + wave * 16;
    int dof = comp * 64;

    __shared__ __align__(16) unsigned short plds[4][16][40];  // pad 32->40

    const unsigned short* qrow = Qb + (size_t)(b * 4096 + q0 + lr) * 128 + dof + lg * 8;
    bf16x8 qf0 = *(const bf16x8*)(qrow);
    bf16x8 qf1 = *(const bf16x8*)(qrow + 32);

    f32x4 o[8];
#pragma unroll
    for (int i = 0; i < 8; ++i) o[i] = f32x4{0.f,0.f,0.f,0.f};
    f32x4 ol = f32x4{0.f,0.f,0.f,0.f};

    bf16x8 ones;
#pragma unroll
    for (int i = 0; i < 8; ++i) ones[i] = (short)0x3F80;  // bf16 1.0

    const unsigned short* kbase = Kb + (size_t)b * 4096 * 128 + dof + lg * 8;
    const unsigned short* vbase = VTb + (size_t)(b * 128 + lr) * 4096 + lg * 8;

    int kstart = split * 2048, kend = kstart + 2048;

    // prefetch first K tile (32 keys) into regs
    const unsigned short* kp0 = kbase + (size_t)(kstart + lr) * 128;
    const unsigned short* kp1 = kbase + (size_t)(kstart + 16 + lr) * 128;
    bf16x8 ka0 = *(const bf16x8*)kp0;
    bf16x8 ka1 = *(const bf16x8*)(kp0 + 32);
    bf16x8 kb0 = *(const bf16x8*)kp1;
    bf16x8 kb1 = *(const bf16x8*)(kp1 + 32);

    for (int k0 = kstart; k0 < kend; k0 += 32) {
        // issue V loads for this tile early (latency hides under exp/LDS)
        bf16x8 vf[8];
#pragma unroll
        for (int vt = 0; vt < 8; ++vt)
            vf[vt] = *(const bf16x8*)(vbase + (size_t)vt * 16 * 4096 + k0);

        f32x4 s0 = f32x4{0.f,0.f,0.f,0.f}, s1 = f32x4{0.f,0.f,0.f,0.f};
        s0 = MFMA16(qf0, ka0, s0); s0 = MFMA16(qf1, ka1, s0);
        s1 = MFMA16(qf0, kb0, s1); s1 = MFMA16(qf1, kb1, s1);

        // prefetch next K tile
        int kn = k0 + 32;
        if (kn < kend) {
            const unsigned short* n0 = kbase + (size_t)(kn + lr) * 128;
            const unsigned short* n1 = kbase + (size_t)(kn + 16 + lr) * 128;
            ka0 = *(const bf16x8*)n0; ka1 = *(const bf16x8*)(n0 + 32);
            kb0 = *(const bf16x8*)n1; kb1 = *(const bf16x8*)(n1 + 32);
        }

        // p = exp2(s) (log2e folded into Q); transpose D-layout -> A-layout via LDS
#pragma unroll
        for (int r = 0; r < 4; ++r) {
            plds[wave][4 * lg + r][lr]      = f2bf(exp2f(s0[r]));
            plds[wave][4 * lg + r][16 + lr] = f2bf(exp2f(s1[r]));
        }
        asm volatile("" ::: "memory");
        bf16x8 pf = *(const bf16x8*)(&plds[wave][lr][lg * 8]);
        asm volatile("" ::: "memory");

        // row-sum via ones-column MFMA (replaces shuffle sum-reduce)
        ol = MFMA16(pf, ones, ol);
#pragma unroll
        for (int vt = 0; vt < 8; ++vt)
            o[vt] = MFMA16(pf, vf[vt], o[vt]);
    }

    int base = (b * 2 + comp) * 2 + split;
    float* op = Opart + (size_t)base * 4096 * 128;
#pragma unroll
    for (int vt = 0; vt < 8; ++vt)
#pragma unroll
        for (int r = 0; r < 4; ++r)
            op[(size_t)(q0 + 4 * lg + r) * 128 + vt * 16 + lr] = o[vt][r];
    if (lr == 0) {
        float* lp = Lpart + (size_t)base * 4096;
#pragma unroll
        for (int r = 0; r < 4; ++r) lp[q0 + 4 * lg + r] = ol[r];
    }
}

// ---------------- Kernel 4: out = O1num/l1 - lam * O2num/l2 ---------------------
__global__ __launch_bounds__(256) void combine(const float* __restrict__ Opart,
        const float* __restrict__ Lpart, const float* __restrict__ lamp,
        float* __restrict__ out) {
    float lam = lamp[0];
    int i = blockIdx.x * 256 + threadIdx.x;   // float4 index over 2*4096*128
    int row = i >> 5;                          // b*4096 + q
    int c4  = i & 31;
    int b = row >> 12, q = row & 4095;

    float l1 = Lpart[((b * 2 + 0) * 2 + 0) * 4096 + q] + Lpart[((b * 2 + 0) * 2 + 1) * 4096 + q];
    float l2 = Lpart[((b * 2 + 1) * 2 + 0) * 4096 + q] + Lpart[((b * 2 + 1) * 2 + 1) * 4096 + q];
    float rl1 = 1.0f / l1, rl2 = 1.0f / l2;

    size_t chunk = (size_t)4096 * 32;          // float4 per (b,comp,split) chunk
    size_t fi = (size_t)q * 32 + c4;
    const float4* O00 = (const float4*)Opart + (size_t)((b * 2 + 0) * 2 + 0) * chunk;
    const float4* O01 = (const float4*)Opart + (size_t)((b * 2 + 0) * 2 + 1) * chunk;
    const float4* O10 = (const float4*)Opart + (size_t)((b * 2 + 1) * 2 + 0) * chunk;
    const float4* O11 = (const float4*)Opart + (size_t)((b * 2 + 1) * 2 + 1) * chunk;

    float4 a0 = O00[fi], a1 = O01[fi], c0 = O10[fi], c1 = O11[fi];
    float4 r;
    r.x = (a0.x + a1.x) * rl1 - lam * (c0.x + c1.x) * rl2;
    r.y = (a0.y + a1.y) * rl1 - lam * (c0.y + c1.y) * rl2;
    r.z = (a0.z + a1.z) * rl1 - lam * (c0.z + c1.z) * rl2;
    r.w = (a0.w + a1.w) * rl1 - lam * (c0.w + c1.w) * rl2;
    ((float4*)out)[i] = r;
}

extern "C" void kernel_launch(void* const* d_in, const int* in_sizes, int n_in,
                              void* d_out, int out_size, void* d_ws, size_t ws_size,
                              hipStream_t stream) {
    const float* X   = (const float*)d_in[0];
    const float* Wq  = (const float*)d_in[1];
    const float* Wk  = (const float*)d_in[2];
    const float* Wv  = (const float*)d_in[3];
    const float* lam = (const float*)d_in[4];
    float* out = (float*)d_out;

    char* ws = (char*)d_ws;
    unsigned short* WT  = (unsigned short*)(ws);                       // 384x1024 bf16
    unsigned short* Qb  = (unsigned short*)(ws + 786432);              // 8192x128 bf16
    unsigned short* Kb  = (unsigned short*)(ws + 786432 + 2097152);    // 8192x128 bf16
    unsigned short* VTb = (unsigned short*)(ws + 786432 + 2*2097152);  // 2x128x4096 bf16
    float* Opart = (float*)(ws + 786432 + 3*2097152);                  // 8x4096x128 f32 (b,comp,split)
    float* Lpart = (float*)(ws + 786432 + 3*2097152 + 33554432);       // 8x4096 f32

    prep_wt<<<dim3(384), dim3(256), 0, stream>>>(Wq, Wk, Wv, WT);
    proj<<<dim3(128, 2), dim3(256), 0, stream>>>(X, WT, Qb, Kb, VTb);
    attn<<<dim3(64, 2, 4), dim3(256), 0, stream>>>(Qb, Kb, VTb, Opart, Lpart);
    combine<<<dim3(1024), dim3(256), 0, stream>>>(Opart, Lpart, lam, out);
}

// Round 3
// 120.963 us; speedup vs baseline: 2.6170x; 1.9799x over previous
//
#include <hip/hip_runtime.h>
#include <hip/hip_bf16.h>

typedef float f32x4 __attribute__((ext_vector_type(4)));
typedef short bf16x8 __attribute__((ext_vector_type(8)));

#define MFMA16(A,B,C) __builtin_amdgcn_mfma_f32_16x16x32_bf16(A,B,C,0,0,0)

__device__ __forceinline__ unsigned short f2bf(float f) {
    union { float f; unsigned u; } x; x.f = f;
    return (unsigned short)((x.u + 0x7FFFu + ((x.u >> 16) & 1u)) >> 16);
}

typedef const __attribute__((address_space(1))) unsigned int* as1_t;
typedef __attribute__((address_space(3))) unsigned int* as3_t;
__device__ __forceinline__ void gl_lds16(const unsigned short* g, unsigned short* l) {
    __builtin_amdgcn_global_load_lds((as1_t)g, (as3_t)l, 16, 0, 0);
}

// ---------------- Kernel 1a: WT[n][k] = W_cat[k][n] bf16, coalesced reads -------
__global__ void prep_wt(const float* __restrict__ Wq, const float* __restrict__ Wk,
                        const float* __restrict__ Wv, unsigned short* __restrict__ WT) {
    int w = blockIdx.x % 3;
    int kt = blockIdx.x / 3;       // 0..31
    const float* src = (w == 0) ? Wq : (w == 1) ? Wk : Wv;
    int k0 = kt * 32;
#pragma unroll
    for (int j = 0; j < 16; ++j) {
        int idx = threadIdx.x + j * 256;       // 0..4095
        int r = idx >> 7, c = idx & 127;
        float v = src[(size_t)(k0 + r) * 128 + c];
        WT[(size_t)(w * 128 + c) * 1024 + k0 + r] = f2bf(v);
    }
}

// ---------------- Kernel 1b: Xb = bf16(X) ---------------------------------------
__global__ __launch_bounds__(256) void prep_x(const float* __restrict__ X,
                                              unsigned short* __restrict__ Xb) {
    int i = blockIdx.x * 256 + threadIdx.x;
#pragma unroll
    for (int r = 0; r < 8; ++r) {
        int idx = i + r * 262144;
        float4 x = ((const float4*)X)[idx];
        ushort4 p;
        p.x = f2bf(x.x); p.y = f2bf(x.y); p.z = f2bf(x.z); p.w = f2bf(x.w);
        ((ushort4*)Xb)[idx] = p;
    }
}

// ---------------- Kernel 2: QKV projection --------------------------------------
__global__ __launch_bounds__(256, 2) void proj(const unsigned short* __restrict__ Xb,
        const unsigned short* __restrict__ WT, unsigned short* __restrict__ Qc,
        unsigned short* __restrict__ Kc, unsigned short* __restrict__ VT) {
    int wave = threadIdx.x >> 6, lane = threadIdx.x & 63;
    int lr = lane & 15, lg = lane >> 4;
    int m0 = blockIdx.x * 64 + wave * 16;
    int nbase = blockIdx.y * 6;

    f32x4 acc[6];
#pragma unroll
    for (int i = 0; i < 6; ++i) acc[i] = f32x4{0.f,0.f,0.f,0.f};

    const unsigned short* xrow = Xb + (size_t)(m0 + lr) * 1024 + lg * 8;
    for (int kk = 0; kk < 1024; kk += 32) {
        bf16x8 a = *(const bf16x8*)(xrow + kk);
#pragma unroll
        for (int nt = 0; nt < 6; ++nt) {
            bf16x8 bfr = *(const bf16x8*)(WT + (size_t)((nbase + nt) * 16 + lr) * 1024 + kk + lg * 8);
            acc[nt] = MFMA16(a, bfr, acc[nt]);
        }
    }
    int b = m0 >> 12;
    int sloc = m0 & 4095;
#pragma unroll
    for (int nt = 0; nt < 6; ++nt) {
        int ntg = nbase + nt;
        if (ntg < 16) {
            int isQ = (ntg < 8);
            int comp = (ntg >> 2) & 1;
            float sc = isQ ? 0.1803368801f : 1.0f;   // (1/8)*log2(e) folded into Q
            unsigned short* dst = isQ ? Qc : Kc;
            int col = (ntg & 3) * 16 + lr;
            size_t rowb = (size_t)(comp * 2 + b) * 4096 + sloc;
#pragma unroll
            for (int r = 0; r < 4; ++r)
                dst[(rowb + 4 * lg + r) * 64 + col] = f2bf(acc[nt][r] * sc);
        } else {
            int vcol = (ntg - 16) * 16 + lr;
            ushort4 pk;
            pk.x = f2bf(acc[nt][0]); pk.y = f2bf(acc[nt][1]);
            pk.z = f2bf(acc[nt][2]); pk.w = f2bf(acc[nt][3]);
            *(ushort4*)(VT + (size_t)(b * 128 + vcol) * 4096 + sloc + 4 * lg) = pk;
        }
    }
}

// ---------------- Kernel 3: flash attention, LDS-staged K/V, 2-phase pipeline ---
__global__ __launch_bounds__(256, 2) void attn(const unsigned short* __restrict__ Qc,
        const unsigned short* __restrict__ Kc, const unsigned short* __restrict__ VT,
        float* __restrict__ Opart, float* __restrict__ Lpart) {
    int tid = threadIdx.x;
    int wave = tid >> 6, lane = tid & 63;
    int lr = lane & 15, lg = lane >> 4;
    int b = blockIdx.y;
    int comp = blockIdx.z >> 1, split = blockIdx.z & 1;
    int q0 = blockIdx.x * 64 + wave * 16;
    int kstart = split * 2048;

    __shared__ __align__(16) unsigned short kbuf[2][64 * 64];
    __shared__ __align__(16) unsigned short vbuf[2][128 * 64];
    __shared__ __align__(16) unsigned short plds[4][16][72];

    const unsigned short* Qp = Qc + ((size_t)(comp * 2 + b) * 4096 + q0 + lr) * 64 + lg * 8;
    bf16x8 qf0 = *(const bf16x8*)(Qp);
    bf16x8 qf1 = *(const bf16x8*)(Qp + 32);

    f32x4 o[8];
#pragma unroll
    for (int i = 0; i < 8; ++i) o[i] = f32x4{0.f,0.f,0.f,0.f};
    f32x4 ol = f32x4{0.f,0.f,0.f,0.f};
    bf16x8 ones;
#pragma unroll
    for (int i = 0; i < 8; ++i) ones[i] = (short)0x3F80;

    int swz = (lane & 7) ^ (lane >> 3);
    const unsigned short* kSrc = Kc + ((size_t)(comp * 2 + b) * 4096 + kstart
                                       + wave * 8 + (lane >> 3)) * 64 + swz * 8;
    const unsigned short* vSrc = VT + ((size_t)b * 128 + (tid >> 3)) * 4096
                                    + kstart + swz * 8;

    int u0 = (lg ^ (lr & 7)) * 8;
    int u1 = ((4 + lg) ^ (lr & 7)) * 8;

    auto STAGE = [&](int bsel, int it) {
        const unsigned short* ks = kSrc + (size_t)it * 4096;
        gl_lds16(ks,        &kbuf[bsel][wave * 512]);
        gl_lds16(ks + 2048, &kbuf[bsel][2048 + wave * 512]);
        const unsigned short* vs = vSrc + it * 64;
#pragma unroll
        for (int ri = 0; ri < 4; ++ri)
            gl_lds16(vs + (size_t)ri * 32 * 4096, &vbuf[bsel][ri * 2048 + wave * 512]);
    };

    STAGE(0, 0);
    __syncthreads();

    for (int it = 0; it < 32; ++it) {
        int cur = it & 1;
        if (it + 1 < 32) STAGE(cur ^ 1, it + 1);

        const unsigned short* kb = &kbuf[cur][0];
        const unsigned short* vb = &vbuf[cur][0];

        f32x4 s[4];
#pragma unroll
        for (int kt = 0; kt < 4; ++kt) {
            int rowoff = (kt * 16 + lr) * 64;
            bf16x8 k0f = *(const bf16x8*)(kb + rowoff + u0);
            bf16x8 k1f = *(const bf16x8*)(kb + rowoff + u1);
            f32x4 sa = f32x4{0.f,0.f,0.f,0.f};
            sa = MFMA16(qf0, k0f, sa);
            sa = MFMA16(qf1, k1f, sa);
            s[kt] = sa;
        }

#pragma unroll
        for (int kt = 0; kt < 4; ++kt)
#pragma unroll
            for (int r = 0; r < 4; ++r)
                plds[wave][4 * lg + r][kt * 16 + lr] = f2bf(__builtin_amdgcn_exp2f(s[kt][r]));
        asm volatile("" ::: "memory");
        bf16x8 pf0 = *(const bf16x8*)(&plds[wave][lr][lg * 8]);
        bf16x8 pf1 = *(const bf16x8*)(&plds[wave][lr][32 + lg * 8]);
        asm volatile("" ::: "memory");

        ol = MFMA16(pf0, ones, ol);
        ol = MFMA16(pf1, ones, ol);
#pragma unroll
        for (int vt = 0; vt < 8; ++vt) {
            int rowoff = (vt * 16 + lr) * 64;
            bf16x8 v0f = *(const bf16x8*)(vb + rowoff + u0);
            bf16x8 v1f = *(const bf16x8*)(vb + rowoff + u1);
            o[vt] = MFMA16(pf0, v0f, o[vt]);
            o[vt] = MFMA16(pf1, v1f, o[vt]);
        }
        __syncthreads();
    }

    int base = (b * 2 + comp) * 2 + split;
    float* op = Opart + (size_t)base * 4096 * 128;
#pragma unroll
    for (int vt = 0; vt < 8; ++vt)
#pragma unroll
        for (int r = 0; r < 4; ++r)
            op[(size_t)(q0 + 4 * lg + r) * 128 + vt * 16 + lr] = o[vt][r];
    if (lr == 0) {
        float* lp = Lpart + (size_t)base * 4096;
#pragma unroll
        for (int r = 0; r < 4; ++r) lp[q0 + 4 * lg + r] = ol[r];
    }
}

// ---------------- Kernel 4: out = O1num/l1 - lam * O2num/l2 ---------------------
__global__ __launch_bounds__(256) void combine(const float* __restrict__ Opart,
        const float* __restrict__ Lpart, const float* __restrict__ lamp,
        float* __restrict__ out) {
    float lam = lamp[0];
    int i = blockIdx.x * 256 + threadIdx.x;
    int row = i >> 5;
    int c4  = i & 31;
    int b = row >> 12, q = row & 4095;

    float l1 = Lpart[((b * 2 + 0) * 2 + 0) * 4096 + q] + Lpart[((b * 2 + 0) * 2 + 1) * 4096 + q];
    float l2 = Lpart[((b * 2 + 1) * 2 + 0) * 4096 + q] + Lpart[((b * 2 + 1) * 2 + 1) * 4096 + q];
    float rl1 = 1.0f / l1, rl2 = 1.0f / l2;

    size_t chunk = (size_t)4096 * 32;
    size_t fi = (size_t)q * 32 + c4;
    const float4* Obase = (const float4*)Opart + (size_t)b * 4 * chunk;
    float4 a0 = Obase[fi];
    float4 a1 = Obase[chunk + fi];
    float4 c0 = Obase[2 * chunk + fi];
    float4 c1 = Obase[3 * chunk + fi];
    float4 r;
    r.x = (a0.x + a1.x) * rl1 - lam * (c0.x + c1.x) * rl2;
    r.y = (a0.y + a1.y) * rl1 - lam * (c0.y + c1.y) * rl2;
    r.z = (a0.z + a1.z) * rl1 - lam * (c0.z + c1.z) * rl2;
    r.w = (a0.w + a1.w) * rl1 - lam * (c0.w + c1.w) * rl2;
    ((float4*)out)[i] = r;
}

extern "C" void kernel_launch(void* const* d_in, const int* in_sizes, int n_in,
                              void* d_out, int out_size, void* d_ws, size_t ws_size,
                              hipStream_t stream) {
    const float* X   = (const float*)d_in[0];
    const float* Wq  = (const float*)d_in[1];
    const float* Wk  = (const float*)d_in[2];
    const float* Wv  = (const float*)d_in[3];
    const float* lam = (const float*)d_in[4];
    float* out = (float*)d_out;

    char* ws = (char*)d_ws;
    unsigned short* WT = (unsigned short*)(ws);                    // 384x1024 bf16
    unsigned short* Xb = (unsigned short*)(ws + 786432);           // 8192x1024 bf16
    unsigned short* Qc = (unsigned short*)(ws + 17563648);         // [2][2][4096][64]
    unsigned short* Kc = (unsigned short*)(ws + 19660800);         // [2][2][4096][64]
    unsigned short* VT = (unsigned short*)(ws + 21757952);         // [2][128][4096]
    float* Opart = (float*)(ws + 23855104);                        // [2][2][2][4096][128] f32 (b,comp,split)
    float* Lpart = (float*)(ws + 40632320);                        // [8][4096] f32

    prep_wt<<<dim3(96), dim3(256), 0, stream>>>(Wq, Wk, Wv, WT);
    prep_x<<<dim3(1024), dim3(256), 0, stream>>>(X, Xb);
    proj<<<dim3(128, 4), dim3(256), 0, stream>>>(Xb, WT, Qc, Kc, VT);
    attn<<<dim3(64, 2, 4), dim3(256), 0, stream>>>(Qc, Kc, VT, Opart, Lpart);
    combine<<<dim3(1024), dim3(256), 0, stream>>>(Opart, Lpart, lam, out);
}

// Round 4
// 93.141 us; speedup vs baseline: 3.3987x; 1.2987x over previous
//
#include <hip/hip_runtime.h>
#include <hip/hip_bf16.h>

typedef float f32x4 __attribute__((ext_vector_type(4)));
typedef short bf16x8 __attribute__((ext_vector_type(8)));

#define MFMA16(A,B,C) __builtin_amdgcn_mfma_f32_16x16x32_bf16(A,B,C,0,0,0)

__device__ __forceinline__ unsigned short f2bf(float f) {
    union { float f; unsigned u; } x; x.f = f;
    return (unsigned short)((x.u + 0x7FFFu + ((x.u >> 16) & 1u)) >> 16);
}

typedef const __attribute__((address_space(1))) unsigned int* as1_t;
typedef __attribute__((address_space(3))) unsigned int* as3_t;
__device__ __forceinline__ void gl_lds16(const unsigned short* g, unsigned short* l) {
    __builtin_amdgcn_global_load_lds((as1_t)g, (as3_t)l, 16, 0, 0);
}

// ---------------- Kernel 1a: WT[n][k] = W_cat[k][n] bf16, coalesced reads -------
__global__ void prep_wt(const float* __restrict__ Wq, const float* __restrict__ Wk,
                        const float* __restrict__ Wv, unsigned short* __restrict__ WT) {
    int w = blockIdx.x % 3;
    int kt = blockIdx.x / 3;       // 0..31
    const float* src = (w == 0) ? Wq : (w == 1) ? Wk : Wv;
    int k0 = kt * 32;
#pragma unroll
    for (int j = 0; j < 16; ++j) {
        int idx = threadIdx.x + j * 256;       // 0..4095
        int r = idx >> 7, c = idx & 127;
        float v = src[(size_t)(k0 + r) * 128 + c];
        WT[(size_t)(w * 128 + c) * 1024 + k0 + r] = f2bf(v);
    }
}

// ---------------- Kernel 1b: Xb = bf16(X) ---------------------------------------
__global__ __launch_bounds__(256) void prep_x(const float* __restrict__ X,
                                              unsigned short* __restrict__ Xb) {
    int i = blockIdx.x * 256 + threadIdx.x;
#pragma unroll
    for (int r = 0; r < 8; ++r) {
        int idx = i + r * 262144;
        float4 x = ((const float4*)X)[idx];
        ushort4 p;
        p.x = f2bf(x.x); p.y = f2bf(x.y); p.z = f2bf(x.z); p.w = f2bf(x.w);
        ((ushort4*)Xb)[idx] = p;
    }
}

// ---------------- Kernel 2: QKV projection, m97-style LDS-staged GEMM ----------
// Tile 128(M) x 96(N), BK=64, double-buffered LDS via global_load_lds w=16.
// Grid (64,4): 256 blocks = 1/CU. 4 waves, each 64x48 output (4x3 16x16 frags).
// Epilogue routes each 16-col frag to Q (scaled, comp-split layout), K, or VT.
__global__ __launch_bounds__(256) void proj(const unsigned short* __restrict__ Xb,
        const unsigned short* __restrict__ WT, unsigned short* __restrict__ Qc,
        unsigned short* __restrict__ Kc, unsigned short* __restrict__ VT) {
    int tid = threadIdx.x;
    int w = tid >> 6, lane = tid & 63;
    int lr = lane & 15, lg = lane >> 4;
    int wr = w >> 1, wc = w & 1;              // 2x2 wave grid
    int m0 = blockIdx.x * 128;
    int n0 = blockIdx.y * 96;

    __shared__ __align__(16) unsigned short Ab[2][128 * 64];  // 16KB x2
    __shared__ __align__(16) unsigned short Bb[2][96 * 64];   // 12KB x2

    f32x4 acc[4][3];
#pragma unroll
    for (int i = 0; i < 4; ++i)
#pragma unroll
        for (int j = 0; j < 3; ++j) acc[i][j] = f32x4{0.f,0.f,0.f,0.f};

    // staging source lane addressing (linear LDS dest; gl_lds = base + lane*16)
    int srow = lane >> 3;                     // 0..7
    int sunit = lane & 7;                     // 16B unit within 128B row
    const unsigned short* aSrc = Xb + (size_t)(m0 + srow) * 1024 + sunit * 8;
    const unsigned short* bSrc = WT + (size_t)(n0 + srow) * 1024 + sunit * 8;

    auto STAGE = [&](int bsel, int st) {
        int kk = st * 64;
#pragma unroll
        for (int i = 0; i < 4; ++i) {         // A: 128 rows, 8 rows per issue
            int blk = w * 4 + i;              // 0..15
            gl_lds16(aSrc + (size_t)blk * 8 * 1024 + kk, &Ab[bsel][blk * 512]);
        }
#pragma unroll
        for (int i = 0; i < 3; ++i) {         // B: 96 rows
            int blk = w * 3 + i;              // 0..11
            gl_lds16(bSrc + (size_t)blk * 8 * 1024 + kk, &Bb[bsel][blk * 512]);
        }
    };

    STAGE(0, 0);
    __syncthreads();

    for (int st = 0; st < 16; ++st) {
        int cur = st & 1;
        if (st + 1 < 16) STAGE(cur ^ 1, st + 1);

        const unsigned short* ab = &Ab[cur][0];
        const unsigned short* bb = &Bb[cur][0];
#pragma unroll
        for (int ksub = 0; ksub < 2; ++ksub) {
            int ko = ksub * 32 + lg * 8;
            bf16x8 af[4], bf[3];
#pragma unroll
            for (int mt = 0; mt < 4; ++mt)
                af[mt] = *(const bf16x8*)(ab + (wr * 64 + mt * 16 + lr) * 64 + ko);
#pragma unroll
            for (int nt = 0; nt < 3; ++nt)
                bf[nt] = *(const bf16x8*)(bb + (wc * 48 + nt * 16 + lr) * 64 + ko);
#pragma unroll
            for (int mt = 0; mt < 4; ++mt)
#pragma unroll
                for (int nt = 0; nt < 3; ++nt)
                    acc[mt][nt] = MFMA16(af[mt], bf[nt], acc[mt][nt]);
        }
        __syncthreads();
    }

    // epilogue: route frags to Q / K / VT
    int b = m0 >> 12;
    int sbase = (m0 & 4095) + wr * 64;
#pragma unroll
    for (int nt = 0; nt < 3; ++nt) {
        int gcol = n0 + wc * 48 + nt * 16 + lr;     // 0..383
        int tensor = gcol >> 7;                     // 0=Q 1=K 2=V
#pragma unroll
        for (int mt = 0; mt < 4; ++mt) {
            int sloc = sbase + mt * 16 + 4 * lg;
            if (tensor == 2) {
                int vcol = gcol & 127;
                ushort4 pk;
                pk.x = f2bf(acc[mt][nt][0]); pk.y = f2bf(acc[mt][nt][1]);
                pk.z = f2bf(acc[mt][nt][2]); pk.w = f2bf(acc[mt][nt][3]);
                *(ushort4*)(VT + (size_t)(b * 128 + vcol) * 4096 + sloc) = pk;
            } else {
                int within = gcol & 127;
                int comp = within >> 6;
                int col64 = within & 63;
                float sc = (tensor == 0) ? 0.1803368801f : 1.0f;  // (1/8)*log2e in Q
                unsigned short* dst = (tensor == 0) ? Qc : Kc;
                size_t rowb = (size_t)(comp * 2 + b) * 4096 + sloc;
#pragma unroll
                for (int r = 0; r < 4; ++r)
                    dst[(rowb + r) * 64 + col64] = f2bf(acc[mt][nt][r] * sc);
            }
        }
    }
}

// ---------------- Kernel 3: flash attention, LDS-staged K/V, 2-phase pipeline ---
__global__ __launch_bounds__(256, 2) void attn(const unsigned short* __restrict__ Qc,
        const unsigned short* __restrict__ Kc, const unsigned short* __restrict__ VT,
        float* __restrict__ Opart, float* __restrict__ Lpart) {
    int tid = threadIdx.x;
    int wave = tid >> 6, lane = tid & 63;
    int lr = lane & 15, lg = lane >> 4;
    int b = blockIdx.y;
    int comp = blockIdx.z >> 1, split = blockIdx.z & 1;
    int q0 = blockIdx.x * 64 + wave * 16;
    int kstart = split * 2048;

    __shared__ __align__(16) unsigned short kbuf[2][64 * 64];
    __shared__ __align__(16) unsigned short vbuf[2][128 * 64];
    __shared__ __align__(16) unsigned short plds[4][16][72];

    const unsigned short* Qp = Qc + ((size_t)(comp * 2 + b) * 4096 + q0 + lr) * 64 + lg * 8;
    bf16x8 qf0 = *(const bf16x8*)(Qp);
    bf16x8 qf1 = *(const bf16x8*)(Qp + 32);

    f32x4 o[8];
#pragma unroll
    for (int i = 0; i < 8; ++i) o[i] = f32x4{0.f,0.f,0.f,0.f};
    f32x4 ol = f32x4{0.f,0.f,0.f,0.f};
    bf16x8 ones;
#pragma unroll
    for (int i = 0; i < 8; ++i) ones[i] = (short)0x3F80;

    int swz = (lane & 7) ^ (lane >> 3);
    const unsigned short* kSrc = Kc + ((size_t)(comp * 2 + b) * 4096 + kstart
                                       + wave * 8 + (lane >> 3)) * 64 + swz * 8;
    const unsigned short* vSrc = VT + ((size_t)b * 128 + (tid >> 3)) * 4096
                                    + kstart + swz * 8;

    int u0 = (lg ^ (lr & 7)) * 8;
    int u1 = ((4 + lg) ^ (lr & 7)) * 8;

    auto STAGE = [&](int bsel, int it) {
        const unsigned short* ks = kSrc + (size_t)it * 4096;
        gl_lds16(ks,        &kbuf[bsel][wave * 512]);
        gl_lds16(ks + 2048, &kbuf[bsel][2048 + wave * 512]);
        const unsigned short* vs = vSrc + it * 64;
#pragma unroll
        for (int ri = 0; ri < 4; ++ri)
            gl_lds16(vs + (size_t)ri * 32 * 4096, &vbuf[bsel][ri * 2048 + wave * 512]);
    };

    STAGE(0, 0);
    __syncthreads();

    for (int it = 0; it < 32; ++it) {
        int cur = it & 1;
        if (it + 1 < 32) STAGE(cur ^ 1, it + 1);

        const unsigned short* kb = &kbuf[cur][0];
        const unsigned short* vb = &vbuf[cur][0];

        f32x4 s[4];
#pragma unroll
        for (int kt = 0; kt < 4; ++kt) {
            int rowoff = (kt * 16 + lr) * 64;
            bf16x8 k0f = *(const bf16x8*)(kb + rowoff + u0);
            bf16x8 k1f = *(const bf16x8*)(kb + rowoff + u1);
            f32x4 sa = f32x4{0.f,0.f,0.f,0.f};
            sa = MFMA16(qf0, k0f, sa);
            sa = MFMA16(qf1, k1f, sa);
            s[kt] = sa;
        }

#pragma unroll
        for (int kt = 0; kt < 4; ++kt)
#pragma unroll
            for (int r = 0; r < 4; ++r)
                plds[wave][4 * lg + r][kt * 16 + lr] = f2bf(__builtin_amdgcn_exp2f(s[kt][r]));
        asm volatile("" ::: "memory");
        bf16x8 pf0 = *(const bf16x8*)(&plds[wave][lr][lg * 8]);
        bf16x8 pf1 = *(const bf16x8*)(&plds[wave][lr][32 + lg * 8]);
        asm volatile("" ::: "memory");

        ol = MFMA16(pf0, ones, ol);
        ol = MFMA16(pf1, ones, ol);
#pragma unroll
        for (int vt = 0; vt < 8; ++vt) {
            int rowoff = (vt * 16 + lr) * 64;
            bf16x8 v0f = *(const bf16x8*)(vb + rowoff + u0);
            bf16x8 v1f = *(const bf16x8*)(vb + rowoff + u1);
            o[vt] = MFMA16(pf0, v0f, o[vt]);
            o[vt] = MFMA16(pf1, v1f, o[vt]);
        }
        __syncthreads();
    }

    int base = (b * 2 + comp) * 2 + split;
    float* op = Opart + (size_t)base * 4096 * 128;
#pragma unroll
    for (int vt = 0; vt < 8; ++vt)
#pragma unroll
        for (int r = 0; r < 4; ++r)
            op[(size_t)(q0 + 4 * lg + r) * 128 + vt * 16 + lr] = o[vt][r];
    if (lr == 0) {
        float* lp = Lpart + (size_t)base * 4096;
#pragma unroll
        for (int r = 0; r < 4; ++r) lp[q0 + 4 * lg + r] = ol[r];
    }
}

// ---------------- Kernel 4: out = O1num/l1 - lam * O2num/l2 ---------------------
__global__ __launch_bounds__(256) void combine(const float* __restrict__ Opart,
        const float* __restrict__ Lpart, const float* __restrict__ lamp,
        float* __restrict__ out) {
    float lam = lamp[0];
    int i = blockIdx.x * 256 + threadIdx.x;
    int row = i >> 5;
    int c4  = i & 31;
    int b = row >> 12, q = row & 4095;

    float l1 = Lpart[((b * 2 + 0) * 2 + 0) * 4096 + q] + Lpart[((b * 2 + 0) * 2 + 1) * 4096 + q];
    float l2 = Lpart[((b * 2 + 1) * 2 + 0) * 4096 + q] + Lpart[((b * 2 + 1) * 2 + 1) * 4096 + q];
    float rl1 = 1.0f / l1, rl2 = 1.0f / l2;

    size_t chunk = (size_t)4096 * 32;
    size_t fi = (size_t)q * 32 + c4;
    const float4* Obase = (const float4*)Opart + (size_t)b * 4 * chunk;
    float4 a0 = Obase[fi];
    float4 a1 = Obase[chunk + fi];
    float4 c0 = Obase[2 * chunk + fi];
    float4 c1 = Obase[3 * chunk + fi];
    float4 r;
    r.x = (a0.x + a1.x) * rl1 - lam * (c0.x + c1.x) * rl2;
    r.y = (a0.y + a1.y) * rl1 - lam * (c0.y + c1.y) * rl2;
    r.z = (a0.z + a1.z) * rl1 - lam * (c0.z + c1.z) * rl2;
    r.w = (a0.w + a1.w) * rl1 - lam * (c0.w + c1.w) * rl2;
    ((float4*)out)[i] = r;
}

extern "C" void kernel_launch(void* const* d_in, const int* in_sizes, int n_in,
                              void* d_out, int out_size, void* d_ws, size_t ws_size,
                              hipStream_t stream) {
    const float* X   = (const float*)d_in[0];
    const float* Wq  = (const float*)d_in[1];
    const float* Wk  = (const float*)d_in[2];
    const float* Wv  = (const float*)d_in[3];
    const float* lam = (const float*)d_in[4];
    float* out = (float*)d_out;

    char* ws = (char*)d_ws;
    unsigned short* WT = (unsigned short*)(ws);                    // 384x1024 bf16
    unsigned short* Xb = (unsigned short*)(ws + 786432);           // 8192x1024 bf16
    unsigned short* Qc = (unsigned short*)(ws + 17563648);         // [2][2][4096][64]
    unsigned short* Kc = (unsigned short*)(ws + 19660800);         // [2][2][4096][64]
    unsigned short* VT = (unsigned short*)(ws + 21757952);         // [2][128][4096]
    float* Opart = (float*)(ws + 23855104);                        // [2][2][2][4096][128] f32
    float* Lpart = (float*)(ws + 40632320);                        // [8][4096] f32

    prep_wt<<<dim3(96), dim3(256), 0, stream>>>(Wq, Wk, Wv, WT);
    prep_x<<<dim3(1024), dim3(256), 0, stream>>>(X, Xb);
    proj<<<dim3(64, 4), dim3(256), 0, stream>>>(Xb, WT, Qc, Kc, VT);
    attn<<<dim3(64, 2, 4), dim3(256), 0, stream>>>(Qc, Kc, VT, Opart, Lpart);
    combine<<<dim3(1024), dim3(256), 0, stream>>>(Opart, Lpart, lam, out);
}

// Round 5
// 88.619 us; speedup vs baseline: 3.5721x; 1.0510x over previous
//
#include <hip/hip_runtime.h>
#include <hip/hip_bf16.h>

typedef float f32x4 __attribute__((ext_vector_type(4)));
typedef short bf16x8 __attribute__((ext_vector_type(8)));

#define MFMA16(A,B,C) __builtin_amdgcn_mfma_f32_16x16x32_bf16(A,B,C,0,0,0)

__device__ __forceinline__ unsigned short f2bf(float f) {
    union { float f; unsigned u; } x; x.f = f;
    return (unsigned short)((x.u + 0x7FFFu + ((x.u >> 16) & 1u)) >> 16);
}

typedef const __attribute__((address_space(1))) unsigned int* as1_t;
typedef __attribute__((address_space(3))) unsigned int* as3_t;
__device__ __forceinline__ void gl_lds16(const unsigned short* g, unsigned short* l) {
    __builtin_amdgcn_global_load_lds((as1_t)g, (as3_t)l, 16, 0, 0);
}

// ---------------- Kernel 1a: WT[n][k] = W_cat[k][n] bf16, coalesced reads -------
__global__ void prep_wt(const float* __restrict__ Wq, const float* __restrict__ Wk,
                        const float* __restrict__ Wv, unsigned short* __restrict__ WT) {
    int w = blockIdx.x % 3;
    int kt = blockIdx.x / 3;       // 0..31
    const float* src = (w == 0) ? Wq : (w == 1) ? Wk : Wv;
    int k0 = kt * 32;
#pragma unroll
    for (int j = 0; j < 16; ++j) {
        int idx = threadIdx.x + j * 256;       // 0..4095
        int r = idx >> 7, c = idx & 127;
        float v = src[(size_t)(k0 + r) * 128 + c];
        WT[(size_t)(w * 128 + c) * 1024 + k0 + r] = f2bf(v);
    }
}

// ---------------- Kernel 1b: Xb = bf16(X) ---------------------------------------
__global__ __launch_bounds__(256) void prep_x(const float* __restrict__ X,
                                              unsigned short* __restrict__ Xb) {
    int i = blockIdx.x * 256 + threadIdx.x;
#pragma unroll
    for (int r = 0; r < 8; ++r) {
        int idx = i + r * 262144;
        float4 x = ((const float4*)X)[idx];
        ushort4 p;
        p.x = f2bf(x.x); p.y = f2bf(x.y); p.z = f2bf(x.z); p.w = f2bf(x.w);
        ((ushort4*)Xb)[idx] = p;
    }
}

// ---------------- Kernel 2: QKV projection, LDS-staged GEMM ---------------------
__global__ __launch_bounds__(256) void proj(const unsigned short* __restrict__ Xb,
        const unsigned short* __restrict__ WT, unsigned short* __restrict__ Qc,
        unsigned short* __restrict__ Kc, unsigned short* __restrict__ VT) {
    int tid = threadIdx.x;
    int w = tid >> 6, lane = tid & 63;
    int lr = lane & 15, lg = lane >> 4;
    int wr = w >> 1, wc = w & 1;              // 2x2 wave grid
    int m0 = blockIdx.x * 128;
    int n0 = blockIdx.y * 96;

    __shared__ __align__(16) unsigned short Ab[2][128 * 64];  // 16KB x2
    __shared__ __align__(16) unsigned short Bb[2][96 * 64];   // 12KB x2

    f32x4 acc[4][3];
#pragma unroll
    for (int i = 0; i < 4; ++i)
#pragma unroll
        for (int j = 0; j < 3; ++j) acc[i][j] = f32x4{0.f,0.f,0.f,0.f};

    int srow = lane >> 3;
    int sunit = lane & 7;
    const unsigned short* aSrc = Xb + (size_t)(m0 + srow) * 1024 + sunit * 8;
    const unsigned short* bSrc = WT + (size_t)(n0 + srow) * 1024 + sunit * 8;

    auto STAGE = [&](int bsel, int st) {
        int kk = st * 64;
#pragma unroll
        for (int i = 0; i < 4; ++i) {
            int blk = w * 4 + i;
            gl_lds16(aSrc + (size_t)blk * 8 * 1024 + kk, &Ab[bsel][blk * 512]);
        }
#pragma unroll
        for (int i = 0; i < 3; ++i) {
            int blk = w * 3 + i;
            gl_lds16(bSrc + (size_t)blk * 8 * 1024 + kk, &Bb[bsel][blk * 512]);
        }
    };

    STAGE(0, 0);
    __syncthreads();

    for (int st = 0; st < 16; ++st) {
        int cur = st & 1;
        if (st + 1 < 16) STAGE(cur ^ 1, st + 1);

        const unsigned short* ab = &Ab[cur][0];
        const unsigned short* bb = &Bb[cur][0];
#pragma unroll
        for (int ksub = 0; ksub < 2; ++ksub) {
            int ko = ksub * 32 + lg * 8;
            bf16x8 af[4], bf[3];
#pragma unroll
            for (int mt = 0; mt < 4; ++mt)
                af[mt] = *(const bf16x8*)(ab + (wr * 64 + mt * 16 + lr) * 64 + ko);
#pragma unroll
            for (int nt = 0; nt < 3; ++nt)
                bf[nt] = *(const bf16x8*)(bb + (wc * 48 + nt * 16 + lr) * 64 + ko);
#pragma unroll
            for (int mt = 0; mt < 4; ++mt)
#pragma unroll
                for (int nt = 0; nt < 3; ++nt)
                    acc[mt][nt] = MFMA16(af[mt], bf[nt], acc[mt][nt]);
        }
        __syncthreads();
    }

    int b = m0 >> 12;
    int sbase = (m0 & 4095) + wr * 64;
#pragma unroll
    for (int nt = 0; nt < 3; ++nt) {
        int gcol = n0 + wc * 48 + nt * 16 + lr;     // 0..383
        int tensor = gcol >> 7;                     // 0=Q 1=K 2=V
#pragma unroll
        for (int mt = 0; mt < 4; ++mt) {
            int sloc = sbase + mt * 16 + 4 * lg;
            if (tensor == 2) {
                int vcol = gcol & 127;
                ushort4 pk;
                pk.x = f2bf(acc[mt][nt][0]); pk.y = f2bf(acc[mt][nt][1]);
                pk.z = f2bf(acc[mt][nt][2]); pk.w = f2bf(acc[mt][nt][3]);
                *(ushort4*)(VT + (size_t)(b * 128 + vcol) * 4096 + sloc) = pk;
            } else {
                int within = gcol & 127;
                int comp = within >> 6;
                int col64 = within & 63;
                float sc = (tensor == 0) ? 0.1803368801f : 1.0f;  // (1/8)*log2e in Q
                unsigned short* dst = (tensor == 0) ? Qc : Kc;
                size_t rowb = (size_t)(comp * 2 + b) * 4096 + sloc;
#pragma unroll
                for (int r = 0; r < 4; ++r)
                    dst[(rowb + r) * 64 + col64] = f2bf(acc[mt][nt][r] * sc);
            }
        }
    }
}

// ---------------- Kernel 3: flash attention, 32 q-rows/wave, 4 K-splits ---------
// blockIdx: x=qtile(128 rows), y=b, z=comp*4+split. 16 KV-tiles of 64 keys.
// K/V LDS fragments read once, used by both q-groups -> half LDS bytes per FLOP.
__global__ __launch_bounds__(256, 2) void attn(const unsigned short* __restrict__ Qc,
        const unsigned short* __restrict__ Kc, const unsigned short* __restrict__ VT,
        float* __restrict__ Opart, float* __restrict__ Lpart) {
    int tid = threadIdx.x;
    int wave = tid >> 6, lane = tid & 63;
    int lr = lane & 15, lg = lane >> 4;
    int b = blockIdx.y;
    int comp = blockIdx.z >> 2, split = blockIdx.z & 3;
    int q0 = blockIdx.x * 128 + wave * 32;
    int kstart = split * 1024;

    __shared__ __align__(16) unsigned short kbuf[2][64 * 64];   // 8KB x2
    __shared__ __align__(16) unsigned short vbuf[2][128 * 64];  // 16KB x2
    __shared__ __align__(16) unsigned short plds[4][16][72];    // 9KB

    // Q fragments for two 16-row groups
    const unsigned short* Qp0 = Qc + ((size_t)(comp * 2 + b) * 4096 + q0 + lr) * 64 + lg * 8;
    const unsigned short* Qp1 = Qp0 + 16 * 64;
    bf16x8 qf00 = *(const bf16x8*)(Qp0);
    bf16x8 qf01 = *(const bf16x8*)(Qp0 + 32);
    bf16x8 qf10 = *(const bf16x8*)(Qp1);
    bf16x8 qf11 = *(const bf16x8*)(Qp1 + 32);

    f32x4 o0[8], o1[8];
#pragma unroll
    for (int i = 0; i < 8; ++i) { o0[i] = f32x4{0.f,0.f,0.f,0.f}; o1[i] = f32x4{0.f,0.f,0.f,0.f}; }
    f32x4 ol0 = f32x4{0.f,0.f,0.f,0.f}, ol1 = f32x4{0.f,0.f,0.f,0.f};
    bf16x8 ones;
#pragma unroll
    for (int i = 0; i < 8; ++i) ones[i] = (short)0x3F80;

    int swz = (lane & 7) ^ (lane >> 3);
    const unsigned short* kSrc = Kc + ((size_t)(comp * 2 + b) * 4096 + kstart
                                       + wave * 8 + (lane >> 3)) * 64 + swz * 8;
    const unsigned short* vSrc = VT + ((size_t)b * 128 + (tid >> 3)) * 4096
                                    + kstart + swz * 8;

    int u0 = (lg ^ (lr & 7)) * 8;
    int u1 = ((4 + lg) ^ (lr & 7)) * 8;

    auto STAGE = [&](int bsel, int it) {
        const unsigned short* ks = kSrc + (size_t)it * 4096;
        gl_lds16(ks,        &kbuf[bsel][wave * 512]);
        gl_lds16(ks + 2048, &kbuf[bsel][2048 + wave * 512]);
        const unsigned short* vs = vSrc + it * 64;
#pragma unroll
        for (int ri = 0; ri < 4; ++ri)
            gl_lds16(vs + (size_t)ri * 32 * 4096, &vbuf[bsel][ri * 2048 + wave * 512]);
    };

    STAGE(0, 0);
    __syncthreads();

    for (int it = 0; it < 16; ++it) {
        int cur = it & 1;
        if (it + 1 < 16) STAGE(cur ^ 1, it + 1);

        const unsigned short* kb = &kbuf[cur][0];
        const unsigned short* vb = &vbuf[cur][0];

        // QK^T for both q-groups, K fragments read once
        f32x4 s0[4], s1[4];
#pragma unroll
        for (int kt = 0; kt < 4; ++kt) {
            int rowoff = (kt * 16 + lr) * 64;
            bf16x8 k0f = *(const bf16x8*)(kb + rowoff + u0);
            bf16x8 k1f = *(const bf16x8*)(kb + rowoff + u1);
            f32x4 a0 = f32x4{0.f,0.f,0.f,0.f};
            f32x4 a1 = f32x4{0.f,0.f,0.f,0.f};
            a0 = MFMA16(qf00, k0f, a0); a0 = MFMA16(qf01, k1f, a0);
            a1 = MFMA16(qf10, k0f, a1); a1 = MFMA16(qf11, k1f, a1);
            s0[kt] = a0; s1[kt] = a1;
        }

        // q-group 0: exp2 -> LDS transpose -> P fragments
#pragma unroll
        for (int kt = 0; kt < 4; ++kt)
#pragma unroll
            for (int r = 0; r < 4; ++r)
                plds[wave][4 * lg + r][kt * 16 + lr] = f2bf(__builtin_amdgcn_exp2f(s0[kt][r]));
        asm volatile("" ::: "memory");
        bf16x8 pf00 = *(const bf16x8*)(&plds[wave][lr][lg * 8]);
        bf16x8 pf01 = *(const bf16x8*)(&plds[wave][lr][32 + lg * 8]);
        asm volatile("" ::: "memory");

        // q-group 1 reuses the same scratch
#pragma unroll
        for (int kt = 0; kt < 4; ++kt)
#pragma unroll
            for (int r = 0; r < 4; ++r)
                plds[wave][4 * lg + r][kt * 16 + lr] = f2bf(__builtin_amdgcn_exp2f(s1[kt][r]));
        asm volatile("" ::: "memory");
        bf16x8 pf10 = *(const bf16x8*)(&plds[wave][lr][lg * 8]);
        bf16x8 pf11 = *(const bf16x8*)(&plds[wave][lr][32 + lg * 8]);
        asm volatile("" ::: "memory");

        ol0 = MFMA16(pf00, ones, ol0); ol0 = MFMA16(pf01, ones, ol0);
        ol1 = MFMA16(pf10, ones, ol1); ol1 = MFMA16(pf11, ones, ol1);

        // PV: V fragments read once, used by both q-groups
#pragma unroll
        for (int vt = 0; vt < 8; ++vt) {
            int rowoff = (vt * 16 + lr) * 64;
            bf16x8 v0f = *(const bf16x8*)(vb + rowoff + u0);
            bf16x8 v1f = *(const bf16x8*)(vb + rowoff + u1);
            o0[vt] = MFMA16(pf00, v0f, o0[vt]);
            o0[vt] = MFMA16(pf01, v1f, o0[vt]);
            o1[vt] = MFMA16(pf10, v0f, o1[vt]);
            o1[vt] = MFMA16(pf11, v1f, o1[vt]);
        }
        __syncthreads();
    }

    int base = (b * 2 + comp) * 4 + split;
    float* op = Opart + (size_t)base * 4096 * 128;
#pragma unroll
    for (int vt = 0; vt < 8; ++vt)
#pragma unroll
        for (int r = 0; r < 4; ++r) {
            op[(size_t)(q0 + 4 * lg + r) * 128 + vt * 16 + lr] = o0[vt][r];
            op[(size_t)(q0 + 16 + 4 * lg + r) * 128 + vt * 16 + lr] = o1[vt][r];
        }
    if (lr == 0) {
        float* lp = Lpart + (size_t)base * 4096;
#pragma unroll
        for (int r = 0; r < 4; ++r) {
            lp[q0 + 4 * lg + r] = ol0[r];
            lp[q0 + 16 + 4 * lg + r] = ol1[r];
        }
    }
}

// ---------------- Kernel 4: out = (SUM O1s)/l1 - lam * (SUM O2s)/l2 --------------
__global__ __launch_bounds__(256) void combine(const float* __restrict__ Opart,
        const float* __restrict__ Lpart, const float* __restrict__ lamp,
        float* __restrict__ out) {
    float lam = lamp[0];
    int i = blockIdx.x * 256 + threadIdx.x;
    int row = i >> 5;
    int c4  = i & 31;
    int b = row >> 12, q = row & 4095;

    float l1 = 0.f, l2 = 0.f;
#pragma unroll
    for (int s = 0; s < 4; ++s) {
        l1 += Lpart[((b * 2 + 0) * 4 + s) * 4096 + q];
        l2 += Lpart[((b * 2 + 1) * 4 + s) * 4096 + q];
    }
    float rl1 = 1.0f / l1, rl2 = 1.0f / l2;

    size_t chunk = (size_t)4096 * 32;
    size_t fi = (size_t)q * 32 + c4;
    const float4* Obase = (const float4*)Opart + (size_t)b * 8 * chunk;
    float4 a = Obase[fi];
    float4 c = Obase[4 * chunk + fi];
#pragma unroll
    for (int s = 1; s < 4; ++s) {
        float4 t1 = Obase[s * chunk + fi];
        float4 t2 = Obase[(4 + s) * chunk + fi];
        a.x += t1.x; a.y += t1.y; a.z += t1.z; a.w += t1.w;
        c.x += t2.x; c.y += t2.y; c.z += t2.z; c.w += t2.w;
    }
    float4 r;
    r.x = a.x * rl1 - lam * c.x * rl2;
    r.y = a.y * rl1 - lam * c.y * rl2;
    r.z = a.z * rl1 - lam * c.z * rl2;
    r.w = a.w * rl1 - lam * c.w * rl2;
    ((float4*)out)[i] = r;
}

extern "C" void kernel_launch(void* const* d_in, const int* in_sizes, int n_in,
                              void* d_out, int out_size, void* d_ws, size_t ws_size,
                              hipStream_t stream) {
    const float* X   = (const float*)d_in[0];
    const float* Wq  = (const float*)d_in[1];
    const float* Wk  = (const float*)d_in[2];
    const float* Wv  = (const float*)d_in[3];
    const float* lam = (const float*)d_in[4];
    float* out = (float*)d_out;

    char* ws = (char*)d_ws;
    // Layout (Opart aliases WT+Xb: proj finishes before attn writes, same stream)
    unsigned short* Qc = (unsigned short*)(ws);                    // [2][2][4096][64]  2MB
    unsigned short* Kc = (unsigned short*)(ws + 2097152);          // [2][2][4096][64]  2MB
    unsigned short* VT = (unsigned short*)(ws + 4194304);          // [2][128][4096]    2MB
    unsigned short* WT = (unsigned short*)(ws + 6291456);          // 384x1024 bf16     768KB
    unsigned short* Xb = (unsigned short*)(ws + 7077888);          // 8192x1024 bf16    16MB
    float* Opart = (float*)(ws + 6291456);                         // [16][4096][128] f32 32MB (alias)
    float* Lpart = (float*)(ws + 39845888);                        // [16][4096] f32
    // end: 40,108,032 bytes

    prep_wt<<<dim3(96), dim3(256), 0, stream>>>(Wq, Wk, Wv, WT);
    prep_x<<<dim3(1024), dim3(256), 0, stream>>>(X, Xb);
    proj<<<dim3(64, 4), dim3(256), 0, stream>>>(Xb, WT, Qc, Kc, VT);
    attn<<<dim3(32, 2, 8), dim3(256), 0, stream>>>(Qc, Kc, VT, Opart, Lpart);
    combine<<<dim3(1024), dim3(256), 0, stream>>>(Opart, Lpart, lam, out);
}

// Round 7
// 87.324 us; speedup vs baseline: 3.6251x; 1.0148x over previous
//
#include <hip/hip_runtime.h>
#include <hip/hip_bf16.h>

typedef float f32x4 __attribute__((ext_vector_type(4)));
typedef float f32x16 __attribute__((ext_vector_type(16)));
typedef short bf16x4 __attribute__((ext_vector_type(4)));
typedef short bf16x8 __attribute__((ext_vector_type(8)));

#define MFMA16(A,B,C) __builtin_amdgcn_mfma_f32_16x16x32_bf16(A,B,C,0,0,0)
#define MFMA32(A,B,C) __builtin_amdgcn_mfma_f32_32x32x16_bf16(A,B,C,0,0,0)

__device__ __forceinline__ unsigned short f2bf(float f) {
    union { float f; unsigned u; } x; x.f = f;
    return (unsigned short)((x.u + 0x7FFFu + ((x.u >> 16) & 1u)) >> 16);
}

__device__ __forceinline__ unsigned pack_bf(float lo, float hi) {
    return (unsigned)f2bf(lo) | ((unsigned)f2bf(hi) << 16);
}

__device__ __forceinline__ f32x16 zero16() {
    f32x16 z;
#pragma unroll
    for (int i = 0; i < 16; ++i) z[i] = 0.f;
    return z;
}

typedef const __attribute__((address_space(1))) unsigned int* as1_t;
typedef __attribute__((address_space(3))) unsigned int* as3_t;
__device__ __forceinline__ void gl_lds16(const unsigned short* g, unsigned short* l) {
    __builtin_amdgcn_global_load_lds((as1_t)g, (as3_t)l, 16, 0, 0);
}

// ---------------- Kernel 1a: WT[n][k] = W_cat[k][n] bf16, coalesced reads -------
__global__ void prep_wt(const float* __restrict__ Wq, const float* __restrict__ Wk,
                        const float* __restrict__ Wv, unsigned short* __restrict__ WT) {
    int w = blockIdx.x % 3;
    int kt = blockIdx.x / 3;       // 0..31
    const float* src = (w == 0) ? Wq : (w == 1) ? Wk : Wv;
    int k0 = kt * 32;
#pragma unroll
    for (int j = 0; j < 16; ++j) {
        int idx = threadIdx.x + j * 256;       // 0..4095
        int r = idx >> 7, c = idx & 127;
        float v = src[(size_t)(k0 + r) * 128 + c];
        WT[(size_t)(w * 128 + c) * 1024 + k0 + r] = f2bf(v);
    }
}

// ---------------- Kernel 1b: Xb = bf16(X) ---------------------------------------
__global__ __launch_bounds__(256) void prep_x(const float* __restrict__ X,
                                              unsigned short* __restrict__ Xb) {
    int i = blockIdx.x * 256 + threadIdx.x;
#pragma unroll
    for (int r = 0; r < 8; ++r) {
        int idx = i + r * 262144;
        float4 x = ((const float4*)X)[idx];
        ushort4 p;
        p.x = f2bf(x.x); p.y = f2bf(x.y); p.z = f2bf(x.z); p.w = f2bf(x.w);
        ((ushort4*)Xb)[idx] = p;
    }
}

// ---------------- Kernel 2: QKV projection, LDS-staged GEMM ---------------------
__global__ __launch_bounds__(256) void proj(const unsigned short* __restrict__ Xb,
        const unsigned short* __restrict__ WT, unsigned short* __restrict__ Qc,
        unsigned short* __restrict__ Kc, unsigned short* __restrict__ VT) {
    int tid = threadIdx.x;
    int w = tid >> 6, lane = tid & 63;
    int lr = lane & 15, lg = lane >> 4;
    int wr = w >> 1, wc = w & 1;              // 2x2 wave grid
    int m0 = blockIdx.x * 128;
    int n0 = blockIdx.y * 96;

    __shared__ __align__(16) unsigned short Ab[2][128 * 64];  // 16KB x2
    __shared__ __align__(16) unsigned short Bb[2][96 * 64];   // 12KB x2

    f32x4 acc[4][3];
#pragma unroll
    for (int i = 0; i < 4; ++i)
#pragma unroll
        for (int j = 0; j < 3; ++j) acc[i][j] = f32x4{0.f,0.f,0.f,0.f};

    int srow = lane >> 3;
    int sunit = lane & 7;
    const unsigned short* aSrc = Xb + (size_t)(m0 + srow) * 1024 + sunit * 8;
    const unsigned short* bSrc = WT + (size_t)(n0 + srow) * 1024 + sunit * 8;

    auto STAGE = [&](int bsel, int st) {
        int kk = st * 64;
#pragma unroll
        for (int i = 0; i < 4; ++i) {
            int blk = w * 4 + i;
            gl_lds16(aSrc + (size_t)blk * 8 * 1024 + kk, &Ab[bsel][blk * 512]);
        }
#pragma unroll
        for (int i = 0; i < 3; ++i) {
            int blk = w * 3 + i;
            gl_lds16(bSrc + (size_t)blk * 8 * 1024 + kk, &Bb[bsel][blk * 512]);
        }
    };

    STAGE(0, 0);
    __syncthreads();

    for (int st = 0; st < 16; ++st) {
        int cur = st & 1;
        if (st + 1 < 16) STAGE(cur ^ 1, st + 1);

        const unsigned short* ab = &Ab[cur][0];
        const unsigned short* bb = &Bb[cur][0];
#pragma unroll
        for (int ksub = 0; ksub < 2; ++ksub) {
            int ko = ksub * 32 + lg * 8;
            bf16x8 af[4], bf[3];
#pragma unroll
            for (int mt = 0; mt < 4; ++mt)
                af[mt] = *(const bf16x8*)(ab + (wr * 64 + mt * 16 + lr) * 64 + ko);
#pragma unroll
            for (int nt = 0; nt < 3; ++nt)
                bf[nt] = *(const bf16x8*)(bb + (wc * 48 + nt * 16 + lr) * 64 + ko);
#pragma unroll
            for (int mt = 0; mt < 4; ++mt)
#pragma unroll
                for (int nt = 0; nt < 3; ++nt)
                    acc[mt][nt] = MFMA16(af[mt], bf[nt], acc[mt][nt]);
        }
        __syncthreads();
    }

    int b = m0 >> 12;
    int sbase = (m0 & 4095) + wr * 64;
#pragma unroll
    for (int nt = 0; nt < 3; ++nt) {
        int gcol = n0 + wc * 48 + nt * 16 + lr;     // 0..383
        int tensor = gcol >> 7;                     // 0=Q 1=K 2=V
#pragma unroll
        for (int mt = 0; mt < 4; ++mt) {
            int sloc = sbase + mt * 16 + 4 * lg;
            if (tensor == 2) {
                int vcol = gcol & 127;
                ushort4 pk;
                pk.x = f2bf(acc[mt][nt][0]); pk.y = f2bf(acc[mt][nt][1]);
                pk.z = f2bf(acc[mt][nt][2]); pk.w = f2bf(acc[mt][nt][3]);
                *(ushort4*)(VT + (size_t)(b * 128 + vcol) * 4096 + sloc) = pk;
            } else {
                int within = gcol & 127;
                int comp = within >> 6;
                int col64 = within & 63;
                float sc = (tensor == 0) ? 0.1803368801f : 1.0f;  // (1/8)*log2e in Q
                unsigned short* dst = (tensor == 0) ? Qc : Kc;
                size_t rowb = (size_t)(comp * 2 + b) * 4096 + sloc;
#pragma unroll
                for (int r = 0; r < 4; ++r)
                    dst[(rowb + r) * 64 + col64] = f2bf(acc[mt][nt][r] * sc);
            }
        }
    }
}

// ---------------- Kernel 3: flash attention, 32x32 MFMA, in-register softmax ----
// Swapped QK^T: S^T = mfma(K,Q), lane owns q-col = q0+(lane&31), 16 keys/tile-half.
// Paired-window PV: A-frag element order == C/D register order (no cross-lane
// movement); V B-frags loaded as 2xb64 chunks matching the same key bijection.
__global__ __launch_bounds__(256, 2) void attn(const unsigned short* __restrict__ Qc,
        const unsigned short* __restrict__ Kc, const unsigned short* __restrict__ VT,
        float* __restrict__ Opart, float* __restrict__ Lpart) {
    int tid = threadIdx.x;
    int wave = tid >> 6, lane = tid & 63;
    int l31 = lane & 31, hi = lane >> 5;
    int x7 = l31 & 7;
    int b = blockIdx.y;
    int comp = blockIdx.z >> 2, split = blockIdx.z & 3;
    int q0 = blockIdx.x * 128 + wave * 32;
    int kstart = split * 1024;

    __shared__ __align__(16) unsigned short kbuf[2][64 * 64];   // 8KB x2
    __shared__ __align__(16) unsigned short vbuf[2][128 * 64];  // 16KB x2

    // Q B-frags: lane holds col q = q0+l31, d = j*16 + hi*8 + e
    const unsigned short* Qp = Qc + ((size_t)(comp * 2 + b) * 4096 + q0 + l31) * 64 + hi * 8;
    bf16x8 qB0 = *(const bf16x8*)(Qp);
    bf16x8 qB1 = *(const bf16x8*)(Qp + 16);
    bf16x8 qB2 = *(const bf16x8*)(Qp + 32);
    bf16x8 qB3 = *(const bf16x8*)(Qp + 48);

    f32x16 o[4];
#pragma unroll
    for (int i = 0; i < 4; ++i) o[i] = zero16();
    float lsum = 0.f;

    int swz = (lane & 7) ^ (lane >> 3);
    const unsigned short* kSrc = Kc + ((size_t)(comp * 2 + b) * 4096 + kstart
                                       + wave * 8 + (lane >> 3)) * 64 + swz * 8;
    const unsigned short* vSrc = VT + ((size_t)b * 128 + (tid >> 3)) * 4096
                                    + kstart + swz * 8;

    auto STAGE = [&](int bsel, int it) {
        const unsigned short* ks = kSrc + (size_t)it * 4096;
        gl_lds16(ks,        &kbuf[bsel][wave * 512]);
        gl_lds16(ks + 2048, &kbuf[bsel][2048 + wave * 512]);
        const unsigned short* vs = vSrc + it * 64;
#pragma unroll
        for (int ri = 0; ri < 4; ++ri)
            gl_lds16(vs + (size_t)ri * 32 * 4096, &vbuf[bsel][ri * 2048 + wave * 512]);
    };

    STAGE(0, 0);
    __syncthreads();

    for (int it = 0; it < 16; ++it) {
        int cur = it & 1;
        if (it + 1 < 16) STAGE(cur ^ 1, it + 1);

        const unsigned short* kb = &kbuf[cur][0];
        const unsigned short* vb = &vbuf[cur][0];

        // S^T[k][q] for two 32-key half-tiles: A = K rows, B = Q cols
        f32x16 st0 = zero16(), st1 = zero16();
#pragma unroll
        for (int j = 0; j < 4; ++j) {
            int ku = ((j * 2 + hi) ^ x7) * 8;
            bf16x8 kA0 = *(const bf16x8*)(kb + l31 * 64 + ku);
            bf16x8 kA1 = *(const bf16x8*)(kb + (32 + l31) * 64 + ku);
            bf16x8 qj = (j == 0) ? qB0 : (j == 1) ? qB1 : (j == 2) ? qB2 : qB3;
            st0 = MFMA32(kA0, qj, st0);
            st1 = MFMA32(kA1, qj, st1);
        }

        // exp2 + pack P straight from accumulator registers (no redistribution).
        // C/D: reg r holds key (r&3)+8*(r>>2)+4*hi; regs 0-7 cover keys 0..15,
        // regs 8-15 cover keys 16..31 -> each group is a valid A-frag whose
        // element e corresponds to key (e&3)+8*(e>>2)+4*hi within its window.
        union W { unsigned u[4]; bf16x8 v; };
        W wA0, wB0, wA1, wB1;
#pragma unroll
        for (int i2 = 0; i2 < 4; ++i2) {
            float a0 = __builtin_amdgcn_exp2f(st0[2 * i2]);
            float a1 = __builtin_amdgcn_exp2f(st0[2 * i2 + 1]);
            float a2 = __builtin_amdgcn_exp2f(st0[8 + 2 * i2]);
            float a3 = __builtin_amdgcn_exp2f(st0[9 + 2 * i2]);
            float b0 = __builtin_amdgcn_exp2f(st1[2 * i2]);
            float b1 = __builtin_amdgcn_exp2f(st1[2 * i2 + 1]);
            float b2 = __builtin_amdgcn_exp2f(st1[8 + 2 * i2]);
            float b3 = __builtin_amdgcn_exp2f(st1[9 + 2 * i2]);
            lsum += (a0 + a1) + (a2 + a3) + (b0 + b1) + (b2 + b3);
            wA0.u[i2] = pack_bf(a0, a1);
            wB0.u[i2] = pack_bf(a2, a3);
            wA1.u[i2] = pack_bf(b0, b1);
            wB1.u[i2] = pack_bf(b2, b3);
        }

        // PV: B-frag element e must read V[key w + (e&3)+8*(e>>2)+4*hi][v]
        // -> two b64 chunks per window at key offsets {w+4hi, w+8+4hi}.
        union VB { bf16x4 h[2]; bf16x8 v; };
        int h4 = 4 * hi;
#pragma unroll
        for (int vt = 0; vt < 4; ++vt) {
            const unsigned short* vrow = vb + (vt * 32 + l31) * 64;
            VB B;
            B.h[0] = *(const bf16x4*)(vrow + ((0 ^ x7) * 8 + h4));
            B.h[1] = *(const bf16x4*)(vrow + ((1 ^ x7) * 8 + h4));
            o[vt] = MFMA32(wA0.v, B.v, o[vt]);
            B.h[0] = *(const bf16x4*)(vrow + ((2 ^ x7) * 8 + h4));
            B.h[1] = *(const bf16x4*)(vrow + ((3 ^ x7) * 8 + h4));
            o[vt] = MFMA32(wB0.v, B.v, o[vt]);
            B.h[0] = *(const bf16x4*)(vrow + ((4 ^ x7) * 8 + h4));
            B.h[1] = *(const bf16x4*)(vrow + ((5 ^ x7) * 8 + h4));
            o[vt] = MFMA32(wA1.v, B.v, o[vt]);
            B.h[0] = *(const bf16x4*)(vrow + ((6 ^ x7) * 8 + h4));
            B.h[1] = *(const bf16x4*)(vrow + ((7 ^ x7) * 8 + h4));
            o[vt] = MFMA32(wB1.v, B.v, o[vt]);
        }
        __syncthreads();
    }

    int base = (b * 2 + comp) * 4 + split;
    float* op = Opart + (size_t)base * 4096 * 128;
#pragma unroll
    for (int vt = 0; vt < 4; ++vt)
#pragma unroll
        for (int r = 0; r < 16; ++r) {
            int qr = (r & 3) + 8 * (r >> 2) + 4 * hi;
            op[(size_t)(q0 + qr) * 128 + vt * 32 + l31] = o[vt][r];
        }
    float lt = lsum + __shfl_xor(lsum, 32, 64);
    if (lane < 32)
        Lpart[(size_t)base * 4096 + q0 + l31] = lt;
}

// ---------------- Kernel 4: out = (SUM O1s)/l1 - lam * (SUM O2s)/l2 --------------
__global__ __launch_bounds__(256) void combine(const float* __restrict__ Opart,
        const float* __restrict__ Lpart, const float* __restrict__ lamp,
        float* __restrict__ out) {
    float lam = lamp[0];
    int i = blockIdx.x * 256 + threadIdx.x;
    int row = i >> 5;
    int c4  = i & 31;
    int b = row >> 12, q = row & 4095;

    float l1 = 0.f, l2 = 0.f;
#pragma unroll
    for (int s = 0; s < 4; ++s) {
        l1 += Lpart[((b * 2 + 0) * 4 + s) * 4096 + q];
        l2 += Lpart[((b * 2 + 1) * 4 + s) * 4096 + q];
    }
    float rl1 = 1.0f / l1, rl2 = 1.0f / l2;

    size_t chunk = (size_t)4096 * 32;
    size_t fi = (size_t)q * 32 + c4;
    const float4* Obase = (const float4*)Opart + (size_t)b * 8 * chunk;
    float4 a = Obase[fi];
    float4 c = Obase[4 * chunk + fi];
#pragma unroll
    for (int s = 1; s < 4; ++s) {
        float4 t1 = Obase[s * chunk + fi];
        float4 t2 = Obase[(4 + s) * chunk + fi];
        a.x += t1.x; a.y += t1.y; a.z += t1.z; a.w += t1.w;
        c.x += t2.x; c.y += t2.y; c.z += t2.z; c.w += t2.w;
    }
    float4 r;
    r.x = a.x * rl1 - lam * c.x * rl2;
    r.y = a.y * rl1 - lam * c.y * rl2;
    r.z = a.z * rl1 - lam * c.z * rl2;
    r.w = a.w * rl1 - lam * c.w * rl2;
    ((float4*)out)[i] = r;
}

extern "C" void kernel_launch(void* const* d_in, const int* in_sizes, int n_in,
                              void* d_out, int out_size, void* d_ws, size_t ws_size,
                              hipStream_t stream) {
    const float* X   = (const float*)d_in[0];
    const float* Wq  = (const float*)d_in[1];
    const float* Wk  = (const float*)d_in[2];
    const float* Wv  = (const float*)d_in[3];
    const float* lam = (const float*)d_in[4];
    float* out = (float*)d_out;

    char* ws = (char*)d_ws;
    // Layout (Opart aliases WT+Xb: proj finishes before attn writes, same stream)
    unsigned short* Qc = (unsigned short*)(ws);                    // [2][2][4096][64]  2MB
    unsigned short* Kc = (unsigned short*)(ws + 2097152);          // [2][2][4096][64]  2MB
    unsigned short* VT = (unsigned short*)(ws + 4194304);          // [2][128][4096]    2MB
    unsigned short* WT = (unsigned short*)(ws + 6291456);          // 384x1024 bf16     768KB
    unsigned short* Xb = (unsigned short*)(ws + 7077888);          // 8192x1024 bf16    16MB
    float* Opart = (float*)(ws + 6291456);                         // [16][4096][128] f32 32MB (alias)
    float* Lpart = (float*)(ws + 39845888);                        // [16][4096] f32
    // end: 40,108,032 bytes

    prep_wt<<<dim3(96), dim3(256), 0, stream>>>(Wq, Wk, Wv, WT);
    prep_x<<<dim3(1024), dim3(256), 0, stream>>>(X, Xb);
    proj<<<dim3(64, 4), dim3(256), 0, stream>>>(Xb, WT, Qc, Kc, VT);
    attn<<<dim3(32, 2, 8), dim3(256), 0, stream>>>(Qc, Kc, VT, Opart, Lpart);
    combine<<<dim3(1024), dim3(256), 0, stream>>>(Opart, Lpart, lam, out);
}

// Round 8
// 81.085 us; speedup vs baseline: 3.9040x; 1.0769x over previous
//
#include <hip/hip_runtime.h>
#include <hip/hip_bf16.h>

typedef float f32x4 __attribute__((ext_vector_type(4)));
typedef float f32x16 __attribute__((ext_vector_type(16)));
typedef short bf16x8 __attribute__((ext_vector_type(8)));

#define MFMA16(A,B,C) __builtin_amdgcn_mfma_f32_16x16x32_bf16(A,B,C,0,0,0)
#define MFMA32(A,B,C) __builtin_amdgcn_mfma_f32_32x32x16_bf16(A,B,C,0,0,0)

__device__ __forceinline__ unsigned short f2bf(float f) {
    union { float f; unsigned u; } x; x.f = f;
    return (unsigned short)((x.u + 0x7FFFu + ((x.u >> 16) & 1u)) >> 16);
}

__device__ __forceinline__ unsigned fbits(float f) {
    union { float f; unsigned u; } x; x.f = f; return x.u;
}

__device__ __forceinline__ f32x16 zero16() {
    f32x16 z;
#pragma unroll
    for (int i = 0; i < 16; ++i) z[i] = 0.f;
    return z;
}

typedef const __attribute__((address_space(1))) unsigned int* as1_t;
typedef __attribute__((address_space(3))) unsigned int* as3_t;
__device__ __forceinline__ void gl_lds16(const unsigned short* g, unsigned short* l) {
    __builtin_amdgcn_global_load_lds((as1_t)g, (as3_t)l, 16, 0, 0);
}

// ---------------- Kernel 1a: WT[n][k] = W_cat[k][n] bf16, coalesced reads -------
__global__ void prep_wt(const float* __restrict__ Wq, const float* __restrict__ Wk,
                        const float* __restrict__ Wv, unsigned short* __restrict__ WT) {
    int w = blockIdx.x % 3;
    int kt = blockIdx.x / 3;       // 0..31
    const float* src = (w == 0) ? Wq : (w == 1) ? Wk : Wv;
    int k0 = kt * 32;
#pragma unroll
    for (int j = 0; j < 16; ++j) {
        int idx = threadIdx.x + j * 256;       // 0..4095
        int r = idx >> 7, c = idx & 127;
        float v = src[(size_t)(k0 + r) * 128 + c];
        WT[(size_t)(w * 128 + c) * 1024 + k0 + r] = f2bf(v);
    }
}

// ---------------- Kernel 1b: Xb = bf16(X) ---------------------------------------
__global__ __launch_bounds__(256) void prep_x(const float* __restrict__ X,
                                              unsigned short* __restrict__ Xb) {
    int i = blockIdx.x * 256 + threadIdx.x;
#pragma unroll
    for (int r = 0; r < 8; ++r) {
        int idx = i + r * 262144;
        float4 x = ((const float4*)X)[idx];
        ushort4 p;
        p.x = f2bf(x.x); p.y = f2bf(x.y); p.z = f2bf(x.z); p.w = f2bf(x.w);
        ((ushort4*)Xb)[idx] = p;
    }
}

// ---------------- Kernel 2: QKV projection, LDS-staged GEMM ---------------------
// BM=64 (grid 128,4 = 512 blocks -> 2/CU, 2 waves/SIMD). V keys stored permuted:
// storage pos = (s & ~15) | swap23(s & 15), so attn PV B-frags are single b128.
__global__ __launch_bounds__(256) void proj(const unsigned short* __restrict__ Xb,
        const unsigned short* __restrict__ WT, unsigned short* __restrict__ Qc,
        unsigned short* __restrict__ Kc, unsigned short* __restrict__ VT) {
    int tid = threadIdx.x;
    int w = tid >> 6, lane = tid & 63;
    int lr = lane & 15, lg = lane >> 4;
    int wr = w >> 1, wc = w & 1;              // 2x2 wave grid
    int m0 = blockIdx.x * 64;
    int n0 = blockIdx.y * 96;

    __shared__ __align__(16) unsigned short Ab[2][64 * 64];   // 8KB x2
    __shared__ __align__(16) unsigned short Bb[2][96 * 64];   // 12KB x2

    f32x4 acc[2][3];
#pragma unroll
    for (int i = 0; i < 2; ++i)
#pragma unroll
        for (int j = 0; j < 3; ++j) acc[i][j] = f32x4{0.f,0.f,0.f,0.f};

    int srow = lane >> 3;
    int sunit = lane & 7;
    const unsigned short* aSrc = Xb + (size_t)(m0 + srow) * 1024 + sunit * 8;
    const unsigned short* bSrc = WT + (size_t)(n0 + srow) * 1024 + sunit * 8;

    auto STAGE = [&](int bsel, int st) {
        int kk = st * 64;
#pragma unroll
        for (int i = 0; i < 2; ++i) {
            int blk = w * 2 + i;              // 0..7
            gl_lds16(aSrc + (size_t)blk * 8 * 1024 + kk, &Ab[bsel][blk * 512]);
        }
#pragma unroll
        for (int i = 0; i < 3; ++i) {
            int blk = w * 3 + i;              // 0..11
            gl_lds16(bSrc + (size_t)blk * 8 * 1024 + kk, &Bb[bsel][blk * 512]);
        }
    };

    STAGE(0, 0);
    __syncthreads();

    for (int st = 0; st < 16; ++st) {
        int cur = st & 1;
        if (st + 1 < 16) STAGE(cur ^ 1, st + 1);

        const unsigned short* ab = &Ab[cur][0];
        const unsigned short* bb = &Bb[cur][0];
#pragma unroll
        for (int ksub = 0; ksub < 2; ++ksub) {
            int ko = ksub * 32 + lg * 8;
            bf16x8 af[2], bf[3];
#pragma unroll
            for (int mt = 0; mt < 2; ++mt)
                af[mt] = *(const bf16x8*)(ab + (wr * 32 + mt * 16 + lr) * 64 + ko);
#pragma unroll
            for (int nt = 0; nt < 3; ++nt)
                bf[nt] = *(const bf16x8*)(bb + (wc * 48 + nt * 16 + lr) * 64 + ko);
#pragma unroll
            for (int mt = 0; mt < 2; ++mt)
#pragma unroll
                for (int nt = 0; nt < 3; ++nt)
                    acc[mt][nt] = MFMA16(af[mt], bf[nt], acc[mt][nt]);
        }
        __syncthreads();
    }

    int b = m0 >> 12;
    int sbase = (m0 & 4095) + wr * 32;
#pragma unroll
    for (int nt = 0; nt < 3; ++nt) {
        int gcol = n0 + wc * 48 + nt * 16 + lr;     // 0..383
        int tensor = gcol >> 7;                     // 0=Q 1=K 2=V
#pragma unroll
        for (int mt = 0; mt < 2; ++mt) {
            int sloc = sbase + mt * 16 + 4 * lg;
            if (tensor == 2) {
                int vcol = gcol & 127;
                // key-permuted storage: 4-key group lg -> group swap(lg bits)
                int slocV = (sloc & ~15) | (((lg & 1) << 3) | ((lg >> 1) << 2));
                ushort4 pk;
                pk.x = f2bf(acc[mt][nt][0]); pk.y = f2bf(acc[mt][nt][1]);
                pk.z = f2bf(acc[mt][nt][2]); pk.w = f2bf(acc[mt][nt][3]);
                *(ushort4*)(VT + (size_t)(b * 128 + vcol) * 4096 + slocV) = pk;
            } else {
                int within = gcol & 127;
                int comp = within >> 6;
                int col64 = within & 63;
                float sc = (tensor == 0) ? 0.1803368801f : 1.0f;  // (1/8)*log2e in Q
                unsigned short* dst = (tensor == 0) ? Qc : Kc;
                size_t rowb = (size_t)(comp * 2 + b) * 4096 + sloc;
#pragma unroll
                for (int r = 0; r < 4; ++r)
                    dst[(rowb + r) * 64 + col64] = f2bf(acc[mt][nt][r] * sc);
            }
        }
    }
}

// ---------------- Kernel 3: flash attention, 32x32 MFMA, in-register softmax ----
// Swapped QK^T: S^T = mfma(K,Q), lane owns q = q0+(lane&31). P packed in-register
// (v_perm truncation); row-sums via ones-MFMA; PV B-frags are single b128 reads
// from the key-permuted V staging (bank-conflict-free).
__global__ __launch_bounds__(256, 2) void attn(const unsigned short* __restrict__ Qc,
        const unsigned short* __restrict__ Kc, const unsigned short* __restrict__ VT,
        float* __restrict__ Opart, float* __restrict__ Lpart) {
    int tid = threadIdx.x;
    int wave = tid >> 6, lane = tid & 63;
    int l31 = lane & 31, hi = lane >> 5;
    int x7 = l31 & 7;
    int b = blockIdx.y;
    int comp = blockIdx.z >> 2, split = blockIdx.z & 3;
    int q0 = blockIdx.x * 128 + wave * 32;
    int kstart = split * 1024;

    __shared__ __align__(16) unsigned short kbuf[2][64 * 64];   // 8KB x2
    __shared__ __align__(16) unsigned short vbuf[2][128 * 64];  // 16KB x2

    // Q B-frags: lane holds col q = q0+l31, d = j*16 + hi*8 + e
    const unsigned short* Qp = Qc + ((size_t)(comp * 2 + b) * 4096 + q0 + l31) * 64 + hi * 8;
    bf16x8 qB0 = *(const bf16x8*)(Qp);
    bf16x8 qB1 = *(const bf16x8*)(Qp + 16);
    bf16x8 qB2 = *(const bf16x8*)(Qp + 32);
    bf16x8 qB3 = *(const bf16x8*)(Qp + 48);

    f32x16 o[4];
#pragma unroll
    for (int i = 0; i < 4; ++i) o[i] = zero16();
    f32x16 ol = zero16();
    bf16x8 ones;
#pragma unroll
    for (int i = 0; i < 8; ++i) ones[i] = (short)0x3F80;

    int swz = (lane & 7) ^ (lane >> 3);
    const unsigned short* kSrc = Kc + ((size_t)(comp * 2 + b) * 4096 + kstart
                                       + wave * 8 + (lane >> 3)) * 64 + swz * 8;
    const unsigned short* vSrc = VT + ((size_t)b * 128 + (tid >> 3)) * 4096
                                    + kstart + swz * 8;

    auto STAGE = [&](int bsel, int it) {
        const unsigned short* ks = kSrc + (size_t)it * 4096;
        gl_lds16(ks,        &kbuf[bsel][wave * 512]);
        gl_lds16(ks + 2048, &kbuf[bsel][2048 + wave * 512]);
        const unsigned short* vs = vSrc + it * 64;
#pragma unroll
        for (int ri = 0; ri < 4; ++ri)
            gl_lds16(vs + (size_t)ri * 32 * 4096, &vbuf[bsel][ri * 2048 + wave * 512]);
    };

    STAGE(0, 0);
    __syncthreads();

    for (int it = 0; it < 16; ++it) {
        int cur = it & 1;
        if (it + 1 < 16) STAGE(cur ^ 1, it + 1);

        const unsigned short* kb = &kbuf[cur][0];
        const unsigned short* vb = &vbuf[cur][0];

        // S^T[k][q] for two 32-key half-tiles: A = K rows, B = Q cols
        f32x16 st0 = zero16(), st1 = zero16();
        __builtin_amdgcn_s_setprio(1);
#pragma unroll
        for (int j = 0; j < 4; ++j) {
            int ku = ((j * 2 + hi) ^ x7) * 8;
            bf16x8 kA0 = *(const bf16x8*)(kb + l31 * 64 + ku);
            bf16x8 kA1 = *(const bf16x8*)(kb + (32 + l31) * 64 + ku);
            bf16x8 qj = (j == 0) ? qB0 : (j == 1) ? qB1 : (j == 2) ? qB2 : qB3;
            st0 = MFMA32(kA0, qj, st0);
            st1 = MFMA32(kA1, qj, st1);
        }
        __builtin_amdgcn_s_setprio(0);

        // exp2 + pack P straight from accumulator registers (v_perm truncation).
        // C/D reg r holds key (r&3)+8*(r>>2)+4*hi: regs 0-7 = window keys 0..15,
        // regs 8-15 = keys 16..31 -> each 8-group is a valid A-frag in reg order.
        union W4 { unsigned u[4]; bf16x8 v; };
        W4 wA0, wB0, wA1, wB1;
#pragma unroll
        for (int i2 = 0; i2 < 4; ++i2) {
            float a0 = __builtin_amdgcn_exp2f(st0[2 * i2]);
            float a1 = __builtin_amdgcn_exp2f(st0[2 * i2 + 1]);
            float a2 = __builtin_amdgcn_exp2f(st0[8 + 2 * i2]);
            float a3 = __builtin_amdgcn_exp2f(st0[9 + 2 * i2]);
            float b0 = __builtin_amdgcn_exp2f(st1[2 * i2]);
            float b1 = __builtin_amdgcn_exp2f(st1[2 * i2 + 1]);
            float b2 = __builtin_amdgcn_exp2f(st1[8 + 2 * i2]);
            float b3 = __builtin_amdgcn_exp2f(st1[9 + 2 * i2]);
            wA0.u[i2] = __builtin_amdgcn_perm(fbits(a1), fbits(a0), 0x07060302);
            wB0.u[i2] = __builtin_amdgcn_perm(fbits(a3), fbits(a2), 0x07060302);
            wA1.u[i2] = __builtin_amdgcn_perm(fbits(b1), fbits(b0), 0x07060302);
            wB1.u[i2] = __builtin_amdgcn_perm(fbits(b3), fbits(b2), 0x07060302);
        }

        // PV + row-sum: B-frag = single b128 at swizzled unit (2W+hi)^x7
        __builtin_amdgcn_s_setprio(1);
        ol = MFMA32(wA0.v, ones, ol);
        ol = MFMA32(wB0.v, ones, ol);
        ol = MFMA32(wA1.v, ones, ol);
        ol = MFMA32(wB1.v, ones, ol);
#pragma unroll
        for (int vt = 0; vt < 4; ++vt) {
            const unsigned short* vrow = vb + (vt * 32 + l31) * 64;
            o[vt] = MFMA32(wA0.v, *(const bf16x8*)(vrow + ((0 + hi) ^ x7) * 8), o[vt]);
            o[vt] = MFMA32(wB0.v, *(const bf16x8*)(vrow + ((2 + hi) ^ x7) * 8), o[vt]);
            o[vt] = MFMA32(wA1.v, *(const bf16x8*)(vrow + ((4 + hi) ^ x7) * 8), o[vt]);
            o[vt] = MFMA32(wB1.v, *(const bf16x8*)(vrow + ((6 + hi) ^ x7) * 8), o[vt]);
        }
        __builtin_amdgcn_s_setprio(0);
        __syncthreads();
    }

    int base = (b * 2 + comp) * 4 + split;
    float* op = Opart + (size_t)base * 4096 * 128;
#pragma unroll
    for (int vt = 0; vt < 4; ++vt)
#pragma unroll
        for (int r = 0; r < 16; ++r) {
            int qr = (r & 3) + 8 * (r >> 2) + 4 * hi;
            op[(size_t)(q0 + qr) * 128 + vt * 32 + l31] = o[vt][r];
        }
    // ol reg r = rowsum(q-row (r&3)+8*(r>>2)+4*hi), identical across cols
    if (l31 == 0) {
        float* lp = Lpart + (size_t)base * 4096 + q0;
#pragma unroll
        for (int r = 0; r < 16; ++r)
            lp[(r & 3) + 8 * (r >> 2) + 4 * hi] = ol[r];
    }
}

// ---------------- Kernel 4: out = (SUM O1s)/l1 - lam * (SUM O2s)/l2 --------------
__global__ __launch_bounds__(256) void combine(const float* __restrict__ Opart,
        const float* __restrict__ Lpart, const float* __restrict__ lamp,
        float* __restrict__ out) {
    float lam = lamp[0];
    int i = blockIdx.x * 256 + threadIdx.x;
    int row = i >> 5;
    int c4  = i & 31;
    int b = row >> 12, q = row & 4095;

    float l1 = 0.f, l2 = 0.f;
#pragma unroll
    for (int s = 0; s < 4; ++s) {
        l1 += Lpart[((b * 2 + 0) * 4 + s) * 4096 + q];
        l2 += Lpart[((b * 2 + 1) * 4 + s) * 4096 + q];
    }
    float rl1 = 1.0f / l1, rl2 = 1.0f / l2;

    size_t chunk = (size_t)4096 * 32;
    size_t fi = (size_t)q * 32 + c4;
    const float4* Obase = (const float4*)Opart + (size_t)b * 8 * chunk;
    float4 a = Obase[fi];
    float4 c = Obase[4 * chunk + fi];
#pragma unroll
    for (int s = 1; s < 4; ++s) {
        float4 t1 = Obase[s * chunk + fi];
        float4 t2 = Obase[(4 + s) * chunk + fi];
        a.x += t1.x; a.y += t1.y; a.z += t1.z; a.w += t1.w;
        c.x += t2.x; c.y += t2.y; c.z += t2.z; c.w += t2.w;
    }
    float4 r;
    r.x = a.x * rl1 - lam * c.x * rl2;
    r.y = a.y * rl1 - lam * c.y * rl2;
    r.z = a.z * rl1 - lam * c.z * rl2;
    r.w = a.w * rl1 - lam * c.w * rl2;
    ((float4*)out)[i] = r;
}

extern "C" void kernel_launch(void* const* d_in, const int* in_sizes, int n_in,
                              void* d_out, int out_size, void* d_ws, size_t ws_size,
                              hipStream_t stream) {
    const float* X   = (const float*)d_in[0];
    const float* Wq  = (const float*)d_in[1];
    const float* Wk  = (const float*)d_in[2];
    const float* Wv  = (const float*)d_in[3];
    const float* lam = (const float*)d_in[4];
    float* out = (float*)d_out;

    char* ws = (char*)d_ws;
    // Layout (Opart aliases WT+Xb: proj finishes before attn writes, same stream)
    unsigned short* Qc = (unsigned short*)(ws);                    // [2][2][4096][64]  2MB
    unsigned short* Kc = (unsigned short*)(ws + 2097152);          // [2][2][4096][64]  2MB
    unsigned short* VT = (unsigned short*)(ws + 4194304);          // [2][128][4096]    2MB
    unsigned short* WT = (unsigned short*)(ws + 6291456);          // 384x1024 bf16     768KB
    unsigned short* Xb = (unsigned short*)(ws + 7077888);          // 8192x1024 bf16    16MB
    float* Opart = (float*)(ws + 6291456);                         // [16][4096][128] f32 32MB (alias)
    float* Lpart = (float*)(ws + 39845888);                        // [16][4096] f32
    // end: 40,108,032 bytes

    prep_wt<<<dim3(96), dim3(256), 0, stream>>>(Wq, Wk, Wv, WT);
    prep_x<<<dim3(1024), dim3(256), 0, stream>>>(X, Xb);
    proj<<<dim3(128, 4), dim3(256), 0, stream>>>(Xb, WT, Qc, Kc, VT);
    attn<<<dim3(32, 2, 8), dim3(256), 0, stream>>>(Qc, Kc, VT, Opart, Lpart);
    combine<<<dim3(1024), dim3(256), 0, stream>>>(Opart, Lpart, lam, out);
}